// Round 5
// baseline (1509.811 us; speedup 1.0000x reference)
//
#include <hip/hip_runtime.h>
#include <hip/hip_bf16.h>
#include <math.h>

#define BB 8
#define NN 256
#define DD 384
#define LL 6
#define HH 8
#define FFD 1536
#define TT 4
#define DH 48
#define NM1 517      // T + 1 + 2N
#define SS 1034      // 2 * NM1
#define SSP 1088     // padded key stride for vt (17*64)
#define MROWS (BB*SS)
#define NQKV 1152
#define QSCALE 0.14433756729740643f

typedef unsigned short u16;
typedef short bf8 __attribute__((ext_vector_type(8)));
typedef float f32x4 __attribute__((ext_vector_type(4)));

__device__ __forceinline__ u16 f2bf(float f) {
  __hip_bfloat16 h = __float2bfloat16(f);
  return *reinterpret_cast<u16*>(&h);
}
__device__ __forceinline__ float bf2f(u16 u) {
  __hip_bfloat16 h;
  *reinterpret_cast<u16*>(&h) = u;
  return __bfloat162float(h);
}
// async global->LDS, 16B per lane; lds dest wave-uniform (HW adds lane*16)
__device__ __forceinline__ void async16(void* lds, const void* g) {
  __builtin_amdgcn_global_load_lds(
      (const __attribute__((address_space(1))) unsigned int*)g,
      (__attribute__((address_space(3))) unsigned int*)lds, 16, 0, 0);
}

// ---------------------------------------------------------------------------
// src assembly: fp32 residual + bf16 mirror.
// ---------------------------------------------------------------------------
__global__ void build_src(const float* __restrict__ hand_t, const float* __restrict__ head_t,
                          const float* __restrict__ hand_m1, const float* __restrict__ head_m1,
                          const float* __restrict__ state_t, const float* __restrict__ state_m1,
                          const float* __restrict__ tok_m1, const float* __restrict__ tok_t,
                          float* __restrict__ src, u16* __restrict__ srcb) {
  int idx = blockIdx.x * 256 + threadIdx.x;
  if (idx >= BB * SS * DD) return;
  int d = idx % DD;
  int bs = idx / DD;
  int s = bs % SS;
  int b = bs / SS;
  float val;
  if (s == 0)               val = state_m1[b * DD + d];
  else if (s <= NN)         val = hand_m1[((size_t)(b * NN + (s - 1))) * DD + d];
  else if (s <= 2 * NN)     val = head_m1[((size_t)(b * NN + (s - 1 - NN))) * DD + d];
  else if (s <= 2 * NN + TT) val = tok_m1[(s - (2 * NN + 1)) * DD + d];
  else if (s == NM1)        val = state_t[b * DD + d];
  else if (s <= NM1 + NN)   val = hand_t[((size_t)(b * NN + (s - NM1 - 1))) * DD + d];
  else if (s <= NM1 + 2 * NN) val = head_t[((size_t)(b * NN + (s - NM1 - 1 - NN))) * DD + d];
  else                      val = tok_t[(s - (NM1 + 2 * NN + 1)) * DD + d];
  src[idx] = val;
  srcb[idx] = f2bf(val);
}

__global__ void build_coords(const float* __restrict__ c_hand_t, const float* __restrict__ c_head_t,
                             const float* __restrict__ c_hand_m1, const float* __restrict__ c_head_m1,
                             const float* __restrict__ tr_t, const float* __restrict__ tr_m1,
                             float* __restrict__ coords) {
  int idx = blockIdx.x * 256 + threadIdx.x;
  if (idx >= BB * SS * 3) return;
  int a = idx % 3;
  int bs = idx / 3;
  int s = bs % SS;
  int b = bs / SS;
  float val;
  if (s == 0)               val = tr_m1[b * 3 + a];
  else if (s <= NN)         val = c_hand_m1[(b * NN + (s - 1)) * 3 + a];
  else if (s <= 2 * NN)     val = c_head_m1[(b * NN + (s - 1 - NN)) * 3 + a];
  else if (s <= 2 * NN + TT) val = tr_m1[b * 3 + a];
  else if (s == NM1)        val = tr_t[b * 3 + a];
  else if (s <= NM1 + NN)   val = c_hand_t[(b * NN + (s - NM1 - 1)) * 3 + a];
  else if (s <= NM1 + 2 * NN) val = c_head_t[(b * NN + (s - NM1 - 1 - NN)) * 3 + a];
  else                      val = tr_t[b * 3 + a];
  coords[idx] = val;
}

// cos/sin table: trig[(b*SS+s)*24 + axis*8 + i] = {cos, sin}(coords*inv_freq)
__global__ void build_trig(const float* __restrict__ coords, float2* __restrict__ trig) {
  int idx = blockIdx.x * 256 + threadIdx.x;
  if (idx >= BB * SS * 24) return;
  int i = idx & 7;
  int axis = (idx >> 3) % 3;
  int bs = idx / 24;
  float cv = coords[bs * 3 + axis];
  float inv = expf(-(float)i * 1.1512925464970229f);  // 10000^(-i/8)
  float ang = cv * inv;
  trig[idx] = make_float2(cosf(ang), sinf(ang));
}

// ---------------------------------------------------------------------------
// weight conversion / packing
// ---------------------------------------------------------------------------
__global__ void cvt_bf(const float* __restrict__ in, u16* __restrict__ out, int n4) {
  int idx = blockIdx.x * 256 + threadIdx.x;
  if (idx >= n4) return;
  float4 v = reinterpret_cast<const float4*>(in)[idx];
  short4 o;
  o.x = (short)f2bf(v.x); o.y = (short)f2bf(v.y);
  o.z = (short)f2bf(v.z); o.w = (short)f2bf(v.w);
  reinterpret_cast<short4*>(out)[idx] = o;
}

__global__ void pack_qkv(const float* __restrict__ Wq, const float* __restrict__ Wk,
                         const float* __restrict__ Wv, u16* __restrict__ wqkv) {
  int idx = blockIdx.x * 256 + threadIdx.x;
  const int TOTAL = LL * NQKV * 96;
  if (idx >= TOTAL) return;
  int k4 = idx % 96;
  int n = (idx / 96) % NQKV;
  int l = idx / (96 * NQKV);
  int sel = n / 384, nn = n - sel * 384;
  const float* W = (sel == 0) ? Wq : ((sel == 1) ? Wk : Wv);
  float4 v = *reinterpret_cast<const float4*>(W + ((size_t)l * 384 + nn) * 384 + k4 * 4);
  short4 o;
  o.x = (short)f2bf(v.x); o.y = (short)f2bf(v.y);
  o.z = (short)f2bf(v.z); o.w = (short)f2bf(v.w);
  *reinterpret_cast<short4*>(wqkv + ((size_t)(l * NQKV + n) * 384 + k4 * 4)) = o;
}

__global__ void pack_bqkv(const float* __restrict__ bq, const float* __restrict__ bk,
                          const float* __restrict__ bv, float* __restrict__ bqkv) {
  int idx = blockIdx.x * 256 + threadIdx.x;
  if (idx >= LL * NQKV) return;
  int n = idx % NQKV, l = idx / NQKV;
  int sel = n / 384, nn = n - sel * 384;
  const float* Bp = (sel == 0) ? bq : ((sel == 1) ? bk : bv);
  bqkv[idx] = Bp[l * 384 + nn];
}

// zero the padded key columns [SS, SSP) of vt
__global__ void pad_vt(u16* __restrict__ vt) {
  int idx = blockIdx.x * 256 + threadIdx.x;
  const int PADW = SSP - SS;
  if (idx >= 64 * DH * PADW) return;
  int c = idx % PADW;
  int rd = idx / PADW;
  vt[(size_t)rd * SSP + SS + c] = 0;
}

// zero the d=48..63 pad of qh/kh (GEMM epilogue writes only d<48)
__global__ void pad_qk(u16* __restrict__ qh, u16* __restrict__ kh) {
  int idx = blockIdx.x * 256 + threadIdx.x;
  if (idx >= 64 * SS * 16) return;
  int c = idx & 15;
  int row = idx >> 4;
  qh[(size_t)row * 64 + 48 + c] = 0;
  kh[(size_t)row * 64 + 48 + c] = 0;
}

// ---------------------------------------------------------------------------
// MFMA GEMM, bf16 in, async global->LDS staging.
//   C[m,n] = sum_k A[m,k]*W[n,k] + bias[n]
//   EPI: 0 none, 1 exact GELU.
//   OUT: 0 fp32 row-major, 1 bf16 row-major, 2 fused-QKV routing WITH RoPE.
// Tile 128x128, BK=64, 4 waves (2x2); each wave owns 64x64 (4x4 accs).
// Per K-step per wave: 16 ds_read_b128 feed 32 MFMA (4x fragment reuse).
// ---------------------------------------------------------------------------
template <int EPI, int OUT>
__global__ __launch_bounds__(256) void gemm_as(
    const u16* __restrict__ Ab, const u16* __restrict__ Wb,
    const float* __restrict__ bias, const float2* __restrict__ trig,
    float* __restrict__ Cf, u16* __restrict__ Cb,
    u16* __restrict__ Ck, u16* __restrict__ Cv,
    int M, int N, int K) {
  __shared__ __align__(16) char sm[32768];  // A 16KB @0, B 16KB @16384
  const int tid = threadIdx.x;
  const int bm = blockIdx.y * 128, bn = blockIdx.x * 128;
  const int lid = tid & 63, w = tid >> 6;
  const int wm = w >> 1, wn = w & 1;
  const int l15 = lid & 15, lg = lid >> 4;
  const int lr = lid >> 3, lu = lid & 7;
  const int swz = lu ^ lr;
  f32x4 acc[4][4] = {};

  for (int k0 = 0; k0 < K; k0 += 64) {
    __syncthreads();
    // A tile: 128 rows x 64 cols bf16; wave w rows [w*32, w*32+32)
#pragma unroll
    for (int q = 0; q < 4; ++q) {
      int row = w * 32 + q * 8 + lr;
      int grow = bm + row; if (grow >= M) grow = M - 1;
      async16(sm + w * 4096 + q * 1024, Ab + (size_t)grow * K + k0 + (swz << 3));
    }
    // B tile: 128 rows x 64 cols bf16
#pragma unroll
    for (int q = 0; q < 4; ++q) {
      int row = w * 32 + q * 8 + lr;
      async16(sm + 16384 + w * 4096 + q * 1024, Wb + (size_t)(bn + row) * K + k0 + (swz << 3));
    }
    __syncthreads();
    bf8 a[2][4], bfr[2][4];
#pragma unroll
    for (int kf = 0; kf < 2; ++kf) {
#pragma unroll
      for (int mt = 0; mt < 4; ++mt) {
        int row = wm * 64 + mt * 16 + l15;
        int off = ((row << 7) + (kf << 6) + (lg << 4)) ^ ((row & 7) << 4);
        a[kf][mt] = *reinterpret_cast<const bf8*>(sm + off);
      }
#pragma unroll
      for (int nt = 0; nt < 4; ++nt) {
        int row = wn * 64 + nt * 16 + l15;
        int off = 16384 + (((row << 7) + (kf << 6) + (lg << 4)) ^ ((row & 7) << 4));
        bfr[kf][nt] = *reinterpret_cast<const bf8*>(sm + off);
      }
    }
#pragma unroll
    for (int kf = 0; kf < 2; ++kf)
#pragma unroll
      for (int mt = 0; mt < 4; ++mt)
#pragma unroll
        for (int nt = 0; nt < 4; ++nt)
          acc[mt][nt] = __builtin_amdgcn_mfma_f32_16x16x32_bf16(a[kf][mt], bfr[kf][nt], acc[mt][nt], 0, 0, 0);
  }

#pragma unroll
  for (int nt = 0; nt < 4; ++nt) {
    const int n = bn + wn * 64 + nt * 16 + l15;
    const float bsv = bias[n];
#pragma unroll
    for (int mt = 0; mt < 4; ++mt) {
      const int m0 = bm + wm * 64 + mt * 16 + lg * 4;
      if (OUT != 2) {
#pragma unroll
        for (int r = 0; r < 4; ++r) {
          int m = m0 + r;
          if (m >= M) continue;
          float v = acc[mt][nt][r] + bsv;
          if (EPI == 1) v = 0.5f * v * (1.0f + erff(v * 0.70710678118654752f));
          if (OUT == 0) Cf[(size_t)m * N + n] = v;
          else          Cb[(size_t)m * N + n] = f2bf(v);
        }
      } else {
        const int sel = n / 384, nn = n - sel * 384;
        const int hdiv = nn / DH, hrem = nn - hdiv * DH;
        const int axis = hrem >> 4, ii = l15 & 7;
        const bool lo = (l15 & 8) == 0;
#pragma unroll
        for (int r = 0; r < 4; ++r) {
          int m = m0 + r;
          int mc = (m < M) ? m : (M - 1);
          float v = acc[mt][nt][r] + bsv;
          float p = __shfl_xor(v, 8);  // rotation partner (d +/- 8)
          int bI = mc / SS, s = mc - bI * SS;
          float outv;
          if (sel < 2) {
            float2 t = trig[(size_t)(bI * SS + s) * 24 + axis * 8 + ii];
            outv = lo ? (v * t.x - p * t.y) : (p * t.y + v * t.x);
            if (sel == 0) outv *= QSCALE;
          } else {
            outv = v;
          }
          if (m < M) {
            int bh = bI * HH + hdiv;
            if (sel == 0)      Cb[((size_t)bh * SS + s) * 64 + hrem] = f2bf(outv);
            else if (sel == 1) Ck[((size_t)bh * SS + s) * 64 + hrem] = f2bf(outv);
            else               Cv[((size_t)bh * DH + hrem) * SSP + s] = f2bf(outv);
          }
        }
      }
    }
  }
}

// ---------------------------------------------------------------------------
// Flash attention v4: 64 queries/WG (4 waves), K/V chunks double-buffered in
// LDS via async global_load_lds (linear dest + pre-swizzled source), ONE
// barrier per chunk (staging of c+1 issued before compute of c).
// ---------------------------------------------------------------------------
__global__ __launch_bounds__(256) void attn_mfma(const u16* __restrict__ qh,
                                                 const u16* __restrict__ kh,
                                                 const u16* __restrict__ vt,
                                                 u16* __restrict__ outb) {
  // buf b: K 8KB @ b*14336, Vt 6KB @ b*14336+8192 ; P @ 28672 + w*2048
  __shared__ __align__(16) char sm[36864];
  const int tid = threadIdx.x;
  const int lid = tid & 63, w = tid >> 6;
  const int l15 = lid & 15, lg = lid >> 4;
  const int lr = lid >> 3, lu = lid & 7;
  const int swz8 = (lu ^ lr) << 3;
  const int qblk = blockIdx.x;
  const int h = blockIdx.y, b = blockIdx.z;
  const int bh = b * HH + h;
  const int q0w = qblk * 64 + w * 16;
  const int PB = 28672 + w * 2048;
  const u16* kbase = kh + (size_t)bh * SS * 64;
  const u16* vbase = vt + (size_t)bh * DH * SSP;

  bf8 qf[2];
  {
    int row = q0w + l15; if (row >= SS) row = SS - 1;
    const u16* qp = qh + ((size_t)bh * SS + row) * 64;
    qf[0] = *reinterpret_cast<const bf8*>(qp + lg * 8);
    qf[1] = *reinterpret_cast<const bf8*>(qp + 32 + lg * 8);
  }

  float m_r[4], l_r[4];
  f32x4 accO[3] = {};
#pragma unroll
  for (int r = 0; r < 4; ++r) { m_r[r] = -1e30f; l_r[r] = 0.f; }

  const int nch = (qblk < 8) ? 9 : 17;

  auto stage = [&](int bsel, int c) {
    const int j0 = c * 64;
    char* kb = sm + bsel * 14336;
    char* vb = kb + 8192;
#pragma unroll
    for (int qq = 0; qq < 2; ++qq) {
      int is = w * 2 + qq;
      int jrow = j0 + is * 8 + lr; if (jrow >= SS) jrow = SS - 1;
      async16(kb + is * 1024, kbase + (size_t)jrow * 64 + swz8);
    }
    async16(vb + w * 1024, vbase + (size_t)(w * 8 + lr) * SSP + j0 + swz8);
    if (w < 2)
      async16(vb + (4 + w) * 1024, vbase + (size_t)((4 + w) * 8 + lr) * SSP + j0 + swz8);
  };

  stage(0, 0);
  __syncthreads();
  int bsel = 0;

  for (int c = 0; c < nch; ++c) {
    if (c + 1 < nch) stage(bsel ^ 1, c + 1);
    const int j0 = c * 64;
    const char* kb = sm + bsel * 14336;
    const char* vb = kb + 8192;

    // QK^T from LDS
    f32x4 sv[4];
#pragma unroll
    for (int jt = 0; jt < 4; ++jt) {
      int row = jt * 16 + l15;
      int off0 = ((row << 7) + (lg << 4)) ^ ((row & 7) << 4);
      int off1 = ((row << 7) + 64 + (lg << 4)) ^ ((row & 7) << 4);
      bf8 kb0 = *reinterpret_cast<const bf8*>(kb + off0);
      bf8 kb1 = *reinterpret_cast<const bf8*>(kb + off1);
      f32x4 z = {};
      z = __builtin_amdgcn_mfma_f32_16x16x32_bf16(qf[0], kb0, z, 0, 0, 0);
      z = __builtin_amdgcn_mfma_f32_16x16x32_bf16(qf[1], kb1, z, 0, 0, 0);
      sv[jt] = z;
    }

    const bool domask = (c == 16) | ((q0w < NM1) & (c >= 8));
    float pv[4][4], alpha[4];
#pragma unroll
    for (int r = 0; r < 4; ++r) {
      float mx = -1e30f;
      if (domask) {
        int qrow = q0w + lg * 4 + r;
#pragma unroll
        for (int jt = 0; jt < 4; ++jt) {
          int jcol = j0 + jt * 16 + l15;
          float s = sv[jt][r];
          if (jcol >= SS || (qrow < NM1 && jcol >= NM1)) s = -1e30f;
          sv[jt][r] = s;
          mx = fmaxf(mx, s);
        }
      } else {
#pragma unroll
        for (int jt = 0; jt < 4; ++jt) mx = fmaxf(mx, sv[jt][r]);
      }
      mx = fmaxf(mx, __shfl_xor(mx, 1));
      mx = fmaxf(mx, __shfl_xor(mx, 2));
      mx = fmaxf(mx, __shfl_xor(mx, 4));
      mx = fmaxf(mx, __shfl_xor(mx, 8));
      float mn = fmaxf(m_r[r], mx);
      alpha[r] = __expf(m_r[r] - mn);
      float ps = 0.f;
#pragma unroll
      for (int jt = 0; jt < 4; ++jt) {
        float p = __expf(sv[jt][r] - mn);
        pv[jt][r] = p;
        ps += p;
      }
      ps += __shfl_xor(ps, 1);
      ps += __shfl_xor(ps, 2);
      ps += __shfl_xor(ps, 4);
      ps += __shfl_xor(ps, 8);
      l_r[r] = l_r[r] * alpha[r] + ps;
      m_r[r] = mn;
    }
#pragma unroll
    for (int dt = 0; dt < 3; ++dt)
#pragma unroll
      for (int r = 0; r < 4; ++r) accO[dt][r] *= alpha[r];

    // P -> per-wave LDS (swizzled) -> A-fragments
#pragma unroll
    for (int jt = 0; jt < 4; ++jt)
#pragma unroll
      for (int r = 0; r < 4; ++r) {
        int qp = lg * 4 + r;
        int off = ((qp << 7) + ((jt * 16 + l15) << 1)) ^ ((qp & 7) << 4);
        *reinterpret_cast<u16*>(sm + PB + off) = f2bf(pv[jt][r]);
      }
    bf8 pa[2];
#pragma unroll
    for (int jc = 0; jc < 2; ++jc) {
      int off = ((l15 << 7) + (jc << 6) + (lg << 4)) ^ ((l15 & 7) << 4);
      pa[jc] = *reinterpret_cast<const bf8*>(sm + PB + off);
    }
    // PV from LDS Vt tile
#pragma unroll
    for (int dt = 0; dt < 3; ++dt) {
      int row = dt * 16 + l15;
#pragma unroll
      for (int jc = 0; jc < 2; ++jc) {
        int off = ((row << 7) + (jc << 6) + (lg << 4)) ^ ((row & 7) << 4);
        bf8 vb8 = *reinterpret_cast<const bf8*>(vb + off);
        accO[dt] = __builtin_amdgcn_mfma_f32_16x16x32_bf16(pa[jc], vb8, accO[dt], 0, 0, 0);
      }
    }
    __syncthreads();  // drains vmcnt (c+1 staged) + frees buf for c+2
    bsel ^= 1;
  }

#pragma unroll
  for (int r = 0; r < 4; ++r) {
    int q = q0w + lg * 4 + r;
    if (q >= SS) continue;
    float inv = 1.0f / l_r[r];
#pragma unroll
    for (int dt = 0; dt < 3; ++dt) {
      int d = dt * 16 + l15;
      outb[((size_t)(b * SS + q)) * DD + h * DH + d] = f2bf(accO[dt][r] * inv);
    }
  }
}

// ---------------------------------------------------------------------------
// out = LayerNorm(a + r) * g + be, fp32 + bf16 mirror.
// ---------------------------------------------------------------------------
__global__ __launch_bounds__(128) void add_ln(const float* __restrict__ a,
                                              const float* __restrict__ r,
                                              const float* __restrict__ g,
                                              const float* __restrict__ be,
                                              float* __restrict__ out,
                                              u16* __restrict__ outb) {
  __shared__ float p1[2], p2[2];
  const int row = blockIdx.x;
  const int t = threadIdx.x;
  const size_t base = (size_t)row * DD;
  float x0 = a[base + t] + r[base + t];
  float x1 = a[base + t + 128] + r[base + t + 128];
  float x2 = a[base + t + 256] + r[base + t + 256];
  float s = x0 + x1 + x2;
#pragma unroll
  for (int off = 32; off; off >>= 1) s += __shfl_xor(s, off);
  if ((t & 63) == 0) p1[t >> 6] = s;
  __syncthreads();
  float mean = (p1[0] + p1[1]) * (1.0f / 384.0f);
  float d0 = x0 - mean, d1 = x1 - mean, d2 = x2 - mean;
  float vsum = d0 * d0 + d1 * d1 + d2 * d2;
#pragma unroll
  for (int off = 32; off; off >>= 1) vsum += __shfl_xor(vsum, off);
  if ((t & 63) == 0) p2[t >> 6] = vsum;
  __syncthreads();
  float var = (p2[0] + p2[1]) * (1.0f / 384.0f);
  float rs = rsqrtf(var + 1e-5f);
  float o0 = d0 * rs * g[t]       + be[t];
  float o1 = d1 * rs * g[t + 128] + be[t + 128];
  float o2 = d2 * rs * g[t + 256] + be[t + 256];
  out[base + t] = o0;        outb[base + t] = f2bf(o0);
  out[base + t + 128] = o1;  outb[base + t + 128] = f2bf(o1);
  out[base + t + 256] = o2;  outb[base + t + 256] = f2bf(o2);
}

__global__ void copy_out(const float* __restrict__ src, float* __restrict__ out) {
  int idx = blockIdx.x * 256 + threadIdx.x;
  if (idx >= BB * TT * DD) return;
  int d = idx % DD;
  int bt = idx / DD;
  int t = bt % TT;
  int b = bt / TT;
  out[idx] = src[((size_t)b * SS + (SS - TT) + t) * DD + d];
}

// ---------------------------------------------------------------------------
extern "C" void kernel_launch(void* const* d_in, const int* in_sizes, int n_in,
                              void* d_out, int out_size, void* d_ws, size_t ws_size,
                              hipStream_t stream) {
  const float* hand_t    = (const float*)d_in[0];
  const float* head_t    = (const float*)d_in[1];
  const float* hand_m1   = (const float*)d_in[2];
  const float* head_m1   = (const float*)d_in[3];
  const float* c_hand_t  = (const float*)d_in[4];
  const float* c_head_t  = (const float*)d_in[5];
  const float* c_hand_m1 = (const float*)d_in[6];
  const float* c_head_m1 = (const float*)d_in[7];
  const float* state_t   = (const float*)d_in[8];
  const float* state_m1  = (const float*)d_in[9];
  const float* tr_t      = (const float*)d_in[10];
  const float* tr_m1     = (const float*)d_in[11];
  const float* tok_m1    = (const float*)d_in[12];
  const float* tok_t     = (const float*)d_in[13];
  const float* Wq = (const float*)d_in[14];
  const float* bq = (const float*)d_in[15];
  const float* Wk = (const float*)d_in[16];
  const float* bk = (const float*)d_in[17];
  const float* Wv = (const float*)d_in[18];
  const float* bv = (const float*)d_in[19];
  const float* Wo = (const float*)d_in[20];
  const float* bo = (const float*)d_in[21];
  const float* W1 = (const float*)d_in[22];
  const float* b1 = (const float*)d_in[23];
  const float* W2 = (const float*)d_in[24];
  const float* b2 = (const float*)d_in[25];
  const float* g1 = (const float*)d_in[26];
  const float* be1 = (const float*)d_in[27];
  const float* g2 = (const float*)d_in[28];
  const float* be2 = (const float*)d_in[29];

  const size_t SRC_N = (size_t)BB * SS * DD;       // 3,176,448
  float* src    = (float*)d_ws;
  float* src2   = src + SRC_N;
  float* bufB   = src2 + SRC_N;
  float* coords = bufB + SRC_N;                    // 24,816
  float* bqkv   = coords + (size_t)BB * SS * 3;    // L*1152
  float2* trig  = (float2*)(bqkv + (size_t)LL * NQKV);   // B*S*24 float2
  u16* srcb  = (u16*)(trig + (size_t)BB * SS * 24);
  u16* src2b = srcb + SRC_N;
  u16* attnb = src2b + SRC_N;
  u16* qh  = attnb + SRC_N;
  const size_t QH_N = (size_t)BB * HH * SS * 64;   // 4,233,216
  u16* khb = qh + QH_N;
  u16* vtb = khb + QH_N;                           // 64*48*1088
  u16* hbf = vtb + (size_t)64 * DH * SSP;          // 12,705,792
  u16* wqkv_b = hbf + (size_t)MROWS * FFD;
  const size_t WD = (size_t)LL * DD * DD;
  const size_t WF = (size_t)LL * FFD * DD;
  u16* wo_bf = wqkv_b + (size_t)LL * NQKV * 384;
  u16* w1_bf = wo_bf + WD;
  u16* w2_bf = w1_bf + WF;

  const int M = MROWS;
  dim3 blk(256);

  build_src<<<(BB * SS * DD + 255) / 256, blk, 0, stream>>>(
      hand_t, head_t, hand_m1, head_m1, state_t, state_m1, tok_m1, tok_t, src, srcb);
  build_coords<<<(BB * SS * 3 + 255) / 256, blk, 0, stream>>>(
      c_hand_t, c_head_t, c_hand_m1, c_head_m1, tr_t, tr_m1, coords);
  build_trig<<<(BB * SS * 24 + 255) / 256, blk, 0, stream>>>(coords, trig);
  pack_qkv<<<(LL * NQKV * 96 + 255) / 256, blk, 0, stream>>>(Wq, Wk, Wv, wqkv_b);
  pack_bqkv<<<(LL * NQKV + 255) / 256, blk, 0, stream>>>(bq, bk, bv, bqkv);
  cvt_bf<<<(int)(WD / 4 + 255) / 256, blk, 0, stream>>>(Wo, wo_bf, (int)(WD / 4));
  cvt_bf<<<(int)(WF / 4 + 255) / 256, blk, 0, stream>>>(W1, w1_bf, (int)(WF / 4));
  cvt_bf<<<(int)(WF / 4 + 255) / 256, blk, 0, stream>>>(W2, w2_bf, (int)(WF / 4));
  pad_vt<<<(64 * DH * (SSP - SS) + 255) / 256, blk, 0, stream>>>(vtb);
  pad_qk<<<(64 * SS * 16 + 255) / 256, blk, 0, stream>>>(qh, khb);

  dim3 gq(DD / 128, (M + 127) / 128);      // (3, 65)
  dim3 gqkv(NQKV / 128, (M + 127) / 128);  // (9, 65)
  dim3 gf1(FFD / 128, (M + 127) / 128);    // (12, 65)
  dim3 gattn((SS + 63) / 64, HH, BB);      // (17, 8, 8)

  for (int l = 0; l < LL; ++l) {
    const u16* Wqkv_l = wqkv_b + (size_t)l * NQKV * 384;
    const u16* Wo_l = wo_bf + (size_t)l * DD * DD;
    const u16* W1_l = w1_bf + (size_t)l * FFD * DD;
    const u16* W2_l = w2_bf + (size_t)l * DD * FFD;

    gemm_as<0, 2><<<gqkv, blk, 0, stream>>>(srcb, Wqkv_l, bqkv + l * NQKV, trig,
                                            nullptr, qh, khb, vtb, M, NQKV, DD);
    attn_mfma<<<gattn, blk, 0, stream>>>(qh, khb, vtb, attnb);
    gemm_as<0, 0><<<gq, blk, 0, stream>>>(attnb, Wo_l, bo + l * DD, nullptr,
                                          bufB, nullptr, nullptr, nullptr, M, DD, DD);
    add_ln<<<M, 128, 0, stream>>>(src, bufB, g1 + l * DD, be1 + l * DD, src2, src2b);
    gemm_as<1, 1><<<gf1, blk, 0, stream>>>(src2b, W1_l, b1 + l * FFD, nullptr,
                                           nullptr, hbf, nullptr, nullptr, M, FFD, DD);
    gemm_as<0, 0><<<gq, blk, 0, stream>>>(hbf, W2_l, b2 + l * DD, nullptr,
                                          bufB, nullptr, nullptr, nullptr, M, DD, FFD);
    add_ln<<<M, 128, 0, stream>>>(src2, bufB, g2 + l * DD, be2 + l * DD, src, srcb);
  }
  copy_out<<<(BB * TT * DD + 255) / 256, blk, 0, stream>>>(src, (float*)d_out);
}

// Round 6
// 1184.030 us; speedup vs baseline: 1.2751x; 1.2751x over previous
//
#include <hip/hip_runtime.h>
#include <hip/hip_bf16.h>
#include <math.h>

#define BB 8
#define NN 256
#define DD 384
#define LL 6
#define HH 8
#define FFD 1536
#define TT 4
#define DH 48
#define NM1 517      // T + 1 + 2N
#define SS 1034      // 2 * NM1
#define SSP 1088     // padded key stride for vt (17*64)
#define MROWS (BB*SS)
#define NQKV 1152
#define QSCALE 0.14433756729740643f

typedef unsigned short u16;
typedef unsigned int u32;
typedef short bf8 __attribute__((ext_vector_type(8)));
typedef float f32x4 __attribute__((ext_vector_type(4)));

__device__ __forceinline__ u16 f2bf(float f) {
  __hip_bfloat16 h = __float2bfloat16(f);
  return *reinterpret_cast<u16*>(&h);
}
__device__ __forceinline__ float bf2f(u16 u) {
  __hip_bfloat16 h;
  *reinterpret_cast<u16*>(&h) = u;
  return __bfloat162float(h);
}
// async global->LDS, 16B per lane; lds dest wave-uniform (HW adds lane*16)
__device__ __forceinline__ void async16(void* lds, const void* g) {
  __builtin_amdgcn_global_load_lds(
      (const __attribute__((address_space(1))) unsigned int*)g,
      (__attribute__((address_space(3))) unsigned int*)lds, 16, 0, 0);
}

// ---------------------------------------------------------------------------
// src assembly: fp32 residual + bf16 mirror.
// ---------------------------------------------------------------------------
__global__ void build_src(const float* __restrict__ hand_t, const float* __restrict__ head_t,
                          const float* __restrict__ hand_m1, const float* __restrict__ head_m1,
                          const float* __restrict__ state_t, const float* __restrict__ state_m1,
                          const float* __restrict__ tok_m1, const float* __restrict__ tok_t,
                          float* __restrict__ src, u16* __restrict__ srcb) {
  int idx = blockIdx.x * 256 + threadIdx.x;
  if (idx >= BB * SS * DD) return;
  int d = idx % DD;
  int bs = idx / DD;
  int s = bs % SS;
  int b = bs / SS;
  float val;
  if (s == 0)               val = state_m1[b * DD + d];
  else if (s <= NN)         val = hand_m1[((size_t)(b * NN + (s - 1))) * DD + d];
  else if (s <= 2 * NN)     val = head_m1[((size_t)(b * NN + (s - 1 - NN))) * DD + d];
  else if (s <= 2 * NN + TT) val = tok_m1[(s - (2 * NN + 1)) * DD + d];
  else if (s == NM1)        val = state_t[b * DD + d];
  else if (s <= NM1 + NN)   val = hand_t[((size_t)(b * NN + (s - NM1 - 1))) * DD + d];
  else if (s <= NM1 + 2 * NN) val = head_t[((size_t)(b * NN + (s - NM1 - 1 - NN))) * DD + d];
  else                      val = tok_t[(s - (NM1 + 2 * NN + 1)) * DD + d];
  src[idx] = val;
  srcb[idx] = f2bf(val);
}

__global__ void build_coords(const float* __restrict__ c_hand_t, const float* __restrict__ c_head_t,
                             const float* __restrict__ c_hand_m1, const float* __restrict__ c_head_m1,
                             const float* __restrict__ tr_t, const float* __restrict__ tr_m1,
                             float* __restrict__ coords) {
  int idx = blockIdx.x * 256 + threadIdx.x;
  if (idx >= BB * SS * 3) return;
  int a = idx % 3;
  int bs = idx / 3;
  int s = bs % SS;
  int b = bs / SS;
  float val;
  if (s == 0)               val = tr_m1[b * 3 + a];
  else if (s <= NN)         val = c_hand_m1[(b * NN + (s - 1)) * 3 + a];
  else if (s <= 2 * NN)     val = c_head_m1[(b * NN + (s - 1 - NN)) * 3 + a];
  else if (s <= 2 * NN + TT) val = tr_m1[b * 3 + a];
  else if (s == NM1)        val = tr_t[b * 3 + a];
  else if (s <= NM1 + NN)   val = c_hand_t[(b * NN + (s - NM1 - 1)) * 3 + a];
  else if (s <= NM1 + 2 * NN) val = c_head_t[(b * NN + (s - NM1 - 1 - NN)) * 3 + a];
  else                      val = tr_t[b * 3 + a];
  coords[idx] = val;
}

// cos/sin table: trig[(b*SS+s)*24 + axis*8 + i] = {cos, sin}(coords*inv_freq)
__global__ void build_trig(const float* __restrict__ coords, float2* __restrict__ trig) {
  int idx = blockIdx.x * 256 + threadIdx.x;
  if (idx >= BB * SS * 24) return;
  int i = idx & 7;
  int axis = (idx >> 3) % 3;
  int bs = idx / 24;
  float cv = coords[bs * 3 + axis];
  float inv = expf(-(float)i * 1.1512925464970229f);  // 10000^(-i/8)
  float ang = cv * inv;
  trig[idx] = make_float2(cosf(ang), sinf(ang));
}

// ---------------------------------------------------------------------------
// weight conversion / packing
// ---------------------------------------------------------------------------
__global__ void cvt_bf(const float* __restrict__ in, u16* __restrict__ out, int n4) {
  int idx = blockIdx.x * 256 + threadIdx.x;
  if (idx >= n4) return;
  float4 v = reinterpret_cast<const float4*>(in)[idx];
  short4 o;
  o.x = (short)f2bf(v.x); o.y = (short)f2bf(v.y);
  o.z = (short)f2bf(v.z); o.w = (short)f2bf(v.w);
  reinterpret_cast<short4*>(out)[idx] = o;
}

__global__ void pack_qkv(const float* __restrict__ Wq, const float* __restrict__ Wk,
                         const float* __restrict__ Wv, u16* __restrict__ wqkv) {
  int idx = blockIdx.x * 256 + threadIdx.x;
  const int TOTAL = LL * NQKV * 96;
  if (idx >= TOTAL) return;
  int k4 = idx % 96;
  int n = (idx / 96) % NQKV;
  int l = idx / (96 * NQKV);
  int sel = n / 384, nn = n - sel * 384;
  const float* W = (sel == 0) ? Wq : ((sel == 1) ? Wk : Wv);
  float4 v = *reinterpret_cast<const float4*>(W + ((size_t)l * 384 + nn) * 384 + k4 * 4);
  short4 o;
  o.x = (short)f2bf(v.x); o.y = (short)f2bf(v.y);
  o.z = (short)f2bf(v.z); o.w = (short)f2bf(v.w);
  *reinterpret_cast<short4*>(wqkv + ((size_t)(l * NQKV + n) * 384 + k4 * 4)) = o;
}

__global__ void pack_bqkv(const float* __restrict__ bq, const float* __restrict__ bk,
                          const float* __restrict__ bv, float* __restrict__ bqkv) {
  int idx = blockIdx.x * 256 + threadIdx.x;
  if (idx >= LL * NQKV) return;
  int n = idx % NQKV, l = idx / NQKV;
  int sel = n / 384, nn = n - sel * 384;
  const float* Bp = (sel == 0) ? bq : ((sel == 1) ? bk : bv);
  bqkv[idx] = Bp[l * 384 + nn];
}

// zero the padded key columns [SS, SSP) of vt
__global__ void pad_vt(u16* __restrict__ vt) {
  int idx = blockIdx.x * 256 + threadIdx.x;
  const int PADW = SSP - SS;
  if (idx >= 64 * DH * PADW) return;
  int c = idx % PADW;
  int rd = idx / PADW;
  vt[(size_t)rd * SSP + SS + c] = 0;
}

// zero the d=48..63 pad of qh/kh (GEMM epilogue writes only d<48)
__global__ void pad_qk(u16* __restrict__ qh, u16* __restrict__ kh) {
  int idx = blockIdx.x * 256 + threadIdx.x;
  if (idx >= 64 * SS * 16) return;
  int c = idx & 15;
  int row = idx >> 4;
  qh[(size_t)row * 64 + 48 + c] = 0;
  kh[(size_t)row * 64 + 48 + c] = 0;
}

// ---------------------------------------------------------------------------
// MFMA GEMM, bf16 in, async global->LDS staging, 2-PHASE double-buffered:
// stage(t+1) issued before compute(t); ONE barrier per K-step.
//   C[m,n] = sum_k A[m,k]*W[n,k] + bias[n]
//   EPI: 0 none, 1 exact GELU.
//   OUT: 0 fp32 row-major, 1 bf16 row-major, 2 fused-QKV routing WITH RoPE.
// Tile 128x64, BK=64, 4 waves (2x2).
// ---------------------------------------------------------------------------
template <int EPI, int OUT>
__global__ __launch_bounds__(256) void gemm_as(
    const u16* __restrict__ Ab, const u16* __restrict__ Wb,
    const float* __restrict__ bias, const float2* __restrict__ trig,
    float* __restrict__ Cf, u16* __restrict__ Cb,
    u16* __restrict__ Ck, u16* __restrict__ Cv,
    int M, int N, int K) {
  __shared__ __align__(16) char sm[49152];  // 2 x (A 16KB + B 8KB)
  const int tid = threadIdx.x;
  const int bm = blockIdx.y * 128, bn = blockIdx.x * 64;
  const int lid = tid & 63, w = tid >> 6;
  const int wm = w >> 1, wn = w & 1;
  const int l15 = lid & 15, lg = lid >> 4;
  const int lr = lid >> 3, lu = lid & 7;
  const int swz = lu ^ lr;
  f32x4 acc[4][2] = {};

  auto stage = [&](int bsel, int k0) {
    char* base = sm + bsel * 24576;
#pragma unroll
    for (int q = 0; q < 4; ++q) {
      int row = w * 32 + q * 8 + lr;
      int grow = bm + row; if (grow >= M) grow = M - 1;
      async16(base + w * 4096 + q * 1024, Ab + (size_t)grow * K + k0 + (swz << 3));
    }
#pragma unroll
    for (int q = 0; q < 2; ++q) {
      int row = w * 16 + q * 8 + lr;
      async16(base + 16384 + w * 2048 + q * 1024, Wb + (size_t)(bn + row) * K + k0 + (swz << 3));
    }
  };

  stage(0, 0);
  __syncthreads();
  int bs = 0;

  for (int k0 = 0; k0 < K; k0 += 64) {
    if (k0 + 64 < K) stage(bs ^ 1, k0 + 64);
    const char* base = sm + bs * 24576;
    bf8 a[2][4], bfr[2][2];
#pragma unroll
    for (int kf = 0; kf < 2; ++kf) {
#pragma unroll
      for (int mt = 0; mt < 4; ++mt) {
        int row = wm * 64 + mt * 16 + l15;
        int off = ((row << 7) + (kf << 6) + (lg << 4)) ^ ((row & 7) << 4);
        a[kf][mt] = *reinterpret_cast<const bf8*>(base + off);
      }
#pragma unroll
      for (int nt = 0; nt < 2; ++nt) {
        int row = wn * 32 + nt * 16 + l15;
        int off = 16384 + (((row << 7) + (kf << 6) + (lg << 4)) ^ ((row & 7) << 4));
        bfr[kf][nt] = *reinterpret_cast<const bf8*>(base + off);
      }
    }
#pragma unroll
    for (int kf = 0; kf < 2; ++kf)
#pragma unroll
      for (int mt = 0; mt < 4; ++mt)
#pragma unroll
        for (int nt = 0; nt < 2; ++nt)
          acc[mt][nt] = __builtin_amdgcn_mfma_f32_16x16x32_bf16(a[kf][mt], bfr[kf][nt], acc[mt][nt], 0, 0, 0);
    __syncthreads();  // drains vmcnt (tile t+1 staged) + frees buf bs
    bs ^= 1;
  }

#pragma unroll
  for (int nt = 0; nt < 2; ++nt) {
    const int n = bn + wn * 32 + nt * 16 + l15;
    const float bsv = bias[n];
#pragma unroll
    for (int mt = 0; mt < 4; ++mt) {
      const int m0 = bm + wm * 64 + mt * 16 + lg * 4;
      if (OUT != 2) {
#pragma unroll
        for (int r = 0; r < 4; ++r) {
          int m = m0 + r;
          if (m >= M) continue;
          float v = acc[mt][nt][r] + bsv;
          if (EPI == 1) v = 0.5f * v * (1.0f + erff(v * 0.70710678118654752f));
          if (OUT == 0) Cf[(size_t)m * N + n] = v;
          else          Cb[(size_t)m * N + n] = f2bf(v);
        }
      } else {
        const int sel = n / 384, nn = n - sel * 384;
        const int hdiv = nn / DH, hrem = nn - hdiv * DH;
        const int axis = hrem >> 4, ii = l15 & 7;
        const bool lo = (l15 & 8) == 0;
#pragma unroll
        for (int r = 0; r < 4; ++r) {
          int m = m0 + r;
          int mc = (m < M) ? m : (M - 1);
          float v = acc[mt][nt][r] + bsv;
          float p = __shfl_xor(v, 8);  // rotation partner (d +/- 8)
          int bI = mc / SS, s = mc - bI * SS;
          float outv;
          if (sel < 2) {
            float2 t = trig[(size_t)(bI * SS + s) * 24 + axis * 8 + ii];
            outv = lo ? (v * t.x - p * t.y) : (p * t.y + v * t.x);
            if (sel == 0) outv *= QSCALE;
          } else {
            outv = v;
          }
          if (m < M) {
            int bh = bI * HH + hdiv;
            if (sel == 0)      Cb[((size_t)bh * SS + s) * 64 + hrem] = f2bf(outv);
            else if (sel == 1) Ck[((size_t)bh * SS + s) * 64 + hrem] = f2bf(outv);
            else               Cv[((size_t)bh * DH + hrem) * SSP + s] = f2bf(outv);
          }
        }
      }
    }
  }
}

// ---------------------------------------------------------------------------
// Flash attention v5: swapped QK^T (mfma(K,Q)) so each lane owns 16 scores of
// ONE query (q = lane&15) -> row reduce = in-register + 2 shfl_xor; P goes
// back to A-fragment form via 16 packed shuffles (no LDS round-trip).
// K/V double-buffered via async global_load_lds, one barrier per chunk.
// 1-D grid with XCD grouping: all 17 qblks of one (b,h) on one XCD,
// long-tail qblks dispatched first.
// ---------------------------------------------------------------------------
__global__ __launch_bounds__(256) void attn_mfma(const u16* __restrict__ qh,
                                                 const u16* __restrict__ kh,
                                                 const u16* __restrict__ vt,
                                                 u16* __restrict__ outb) {
  // buf b: K 8KB @ b*14336, Vt 6KB @ b*14336+8192
  __shared__ __align__(16) char sm[28672];
  const int tid = threadIdx.x;
  const int lid = tid & 63, w = tid >> 6;
  const int l15 = lid & 15, lg = lid >> 4;
  const int lr = lid >> 3, lu = lid & 7;
  const int swz8 = (lu ^ lr) << 3;

  // XCD-grouped remap: f = low(3b: xcd) + 8*( gi*17 + qp17 )
  const int f = blockIdx.x;
  const int low = f & 7, j = f >> 3;
  const int gi = j / 17, qp17 = j - gi * 17;
  const int g = gi * 8 + low;          // (b,h) group
  const int h = g & 7, b = g >> 3;
  const int qblk = 16 - qp17;          // long (17-chunk) blocks first
  const int bh = b * HH + h;
  const int q0w = qblk * 64 + w * 16;
  const u16* kbase = kh + (size_t)bh * SS * 64;
  const u16* vbase = vt + (size_t)bh * DH * SSP;

  bf8 qf[2];
  {
    int row = q0w + l15; if (row >= SS) row = SS - 1;
    const u16* qp = qh + ((size_t)bh * SS + row) * 64;
    qf[0] = *reinterpret_cast<const bf8*>(qp + lg * 8);
    qf[1] = *reinterpret_cast<const bf8*>(qp + 32 + lg * 8);
  }
  const int qrow = q0w + l15;   // this lane's query (for mask + softmax state)

  float m_q = -1e30f, l_q = 0.f;
  f32x4 accO[3] = {};

  const int nch = (qblk < 8) ? 9 : 17;

  auto stage = [&](int bsel, int c) {
    const int j0 = c * 64;
    char* kb = sm + bsel * 14336;
    char* vb = kb + 8192;
#pragma unroll
    for (int qq = 0; qq < 2; ++qq) {
      int is = w * 2 + qq;
      int jrow = j0 + is * 8 + lr; if (jrow >= SS) jrow = SS - 1;
      async16(kb + is * 1024, kbase + (size_t)jrow * 64 + swz8);
    }
    async16(vb + w * 1024, vbase + (size_t)(w * 8 + lr) * SSP + j0 + swz8);
    if (w < 2)
      async16(vb + (4 + w) * 1024, vbase + (size_t)((4 + w) * 8 + lr) * SSP + j0 + swz8);
  };

  stage(0, 0);
  __syncthreads();
  int bsel = 0;

  for (int c = 0; c < nch; ++c) {
    if (c + 1 < nch) stage(bsel ^ 1, c + 1);
    const int j0 = c * 64;
    const char* kb = sm + bsel * 14336;
    const char* vb = kb + 8192;

    // QK^T swapped: sv[jt][r] = S[key = j0+jt*16+lg*4+r][q = l15]
    f32x4 sv[4];
#pragma unroll
    for (int jt = 0; jt < 4; ++jt) {
      int row = jt * 16 + l15;
      int off0 = ((row << 7) + (lg << 4)) ^ ((row & 7) << 4);
      int off1 = ((row << 7) + 64 + (lg << 4)) ^ ((row & 7) << 4);
      bf8 kb0 = *reinterpret_cast<const bf8*>(kb + off0);
      bf8 kb1 = *reinterpret_cast<const bf8*>(kb + off1);
      f32x4 z = {};
      z = __builtin_amdgcn_mfma_f32_16x16x32_bf16(kb0, qf[0], z, 0, 0, 0);
      z = __builtin_amdgcn_mfma_f32_16x16x32_bf16(kb1, qf[1], z, 0, 0, 0);
      sv[jt] = z;
    }

    const bool domask = (c == 16) | ((q0w < NM1) & (c >= 8));
    if (domask) {
#pragma unroll
      for (int jt = 0; jt < 4; ++jt)
#pragma unroll
        for (int r = 0; r < 4; ++r) {
          int kabs = j0 + jt * 16 + lg * 4 + r;
          if (kabs >= SS || (qrow < NM1 && kabs >= NM1)) sv[jt][r] = -1e30f;
        }
    }

    // row max: 16 in-register + 2 cross-group shfl
    float mx = sv[0][0];
#pragma unroll
    for (int jt = 0; jt < 4; ++jt)
#pragma unroll
      for (int r = 0; r < 4; ++r) mx = fmaxf(mx, sv[jt][r]);
    mx = fmaxf(mx, __shfl_xor(mx, 16));
    mx = fmaxf(mx, __shfl_xor(mx, 32));

    const bool skip = __all(mx <= m_q);   // T13: no new max anywhere -> no rescale
    const float mn = skip ? m_q : fmaxf(m_q, mx);

    float pv[4][4];
    float ps = 0.f;
#pragma unroll
    for (int jt = 0; jt < 4; ++jt)
#pragma unroll
      for (int r = 0; r < 4; ++r) {
        float p = __expf(sv[jt][r] - mn);
        pv[jt][r] = p;
        ps += p;
      }
    ps += __shfl_xor(ps, 16);
    ps += __shfl_xor(ps, 32);

    if (!skip) {
      float alpha = __expf(m_q - mn);
      l_q = l_q * alpha + ps;
      m_q = mn;
      const int lg4 = lg * 4;
      float a0 = __shfl(alpha, lg4);
      float a1 = __shfl(alpha, lg4 + 1);
      float a2 = __shfl(alpha, lg4 + 2);
      float a3 = __shfl(alpha, lg4 + 3);
#pragma unroll
      for (int dt = 0; dt < 3; ++dt) {
        accO[dt][0] *= a0; accO[dt][1] *= a1;
        accO[dt][2] *= a2; accO[dt][3] *= a3;
      }
    } else {
      l_q += ps;
    }

    // pack P to bf16 pairs: P2[jt][h] = {pv[jt][2h], pv[jt][2h+1]}
    u32 P2[4][2];
#pragma unroll
    for (int jt = 0; jt < 4; ++jt)
#pragma unroll
      for (int hh = 0; hh < 2; ++hh)
        P2[jt][hh] = (u32)f2bf(pv[jt][2 * hh]) | ((u32)f2bf(pv[jt][2 * hh + 1]) << 16);

    // redistribute to A-fragment: pa[kf] slot m = P[q=l15][k=kf*32+lg*8+m]
    u32 paw0[4], paw1[4];
    const bool selhi = (lg & 2) != 0;
#pragma unroll
    for (int u = 0; u < 4; ++u) {
      int srcLane = l15 + (((lg & 1) * 2 + (u >> 1)) << 4);
      u32 s00 = __shfl(P2[0][u & 1], srcLane);
      u32 s01 = __shfl(P2[1][u & 1], srcLane);
      u32 s10 = __shfl(P2[2][u & 1], srcLane);
      u32 s11 = __shfl(P2[3][u & 1], srcLane);
      paw0[u] = selhi ? s01 : s00;
      paw1[u] = selhi ? s11 : s10;
    }
    uint4 t0 = make_uint4(paw0[0], paw0[1], paw0[2], paw0[3]);
    uint4 t1 = make_uint4(paw1[0], paw1[1], paw1[2], paw1[3]);
    bf8 pa[2];
    pa[0] = *reinterpret_cast<bf8*>(&t0);
    pa[1] = *reinterpret_cast<bf8*>(&t1);

    // PV from LDS Vt tile
#pragma unroll
    for (int dt = 0; dt < 3; ++dt) {
      int row = dt * 16 + l15;
#pragma unroll
      for (int jc = 0; jc < 2; ++jc) {
        int off = ((row << 7) + (jc << 6) + (lg << 4)) ^ ((row & 7) << 4);
        bf8 vb8 = *reinterpret_cast<const bf8*>(vb + off);
        accO[dt] = __builtin_amdgcn_mfma_f32_16x16x32_bf16(pa[jc], vb8, accO[dt], 0, 0, 0);
      }
    }
    __syncthreads();  // drains vmcnt (c+1 staged) + frees buf for c+2
    bsel ^= 1;
  }

  // epilogue: fetch 1/l for the 4 output rows (q = q0w + lg*4 + r)
  float linv = 1.0f / l_q;
  const int lg4 = lg * 4;
  float il[4];
#pragma unroll
  for (int r = 0; r < 4; ++r) il[r] = __shfl(linv, lg4 + r);
#pragma unroll
  for (int r = 0; r < 4; ++r) {
    int q = q0w + lg4 + r;
    if (q >= SS) continue;
#pragma unroll
    for (int dt = 0; dt < 3; ++dt) {
      int d = dt * 16 + l15;
      outb[((size_t)(b * SS + q)) * DD + h * DH + d] = f2bf(accO[dt][r] * il[r]);
    }
  }
}

// ---------------------------------------------------------------------------
// out = LayerNorm(a + r) * g + be, fp32 + bf16 mirror.
// ---------------------------------------------------------------------------
__global__ __launch_bounds__(128) void add_ln(const float* __restrict__ a,
                                              const float* __restrict__ r,
                                              const float* __restrict__ g,
                                              const float* __restrict__ be,
                                              float* __restrict__ out,
                                              u16* __restrict__ outb) {
  __shared__ float p1[2], p2[2];
  const int row = blockIdx.x;
  const int t = threadIdx.x;
  const size_t base = (size_t)row * DD;
  float x0 = a[base + t] + r[base + t];
  float x1 = a[base + t + 128] + r[base + t + 128];
  float x2 = a[base + t + 256] + r[base + t + 256];
  float s = x0 + x1 + x2;
#pragma unroll
  for (int off = 32; off; off >>= 1) s += __shfl_xor(s, off);
  if ((t & 63) == 0) p1[t >> 6] = s;
  __syncthreads();
  float mean = (p1[0] + p1[1]) * (1.0f / 384.0f);
  float d0 = x0 - mean, d1 = x1 - mean, d2 = x2 - mean;
  float vsum = d0 * d0 + d1 * d1 + d2 * d2;
#pragma unroll
  for (int off = 32; off; off >>= 1) vsum += __shfl_xor(vsum, off);
  if ((t & 63) == 0) p2[t >> 6] = vsum;
  __syncthreads();
  float var = (p2[0] + p2[1]) * (1.0f / 384.0f);
  float rs = rsqrtf(var + 1e-5f);
  float o0 = d0 * rs * g[t]       + be[t];
  float o1 = d1 * rs * g[t + 128] + be[t + 128];
  float o2 = d2 * rs * g[t + 256] + be[t + 256];
  out[base + t] = o0;        outb[base + t] = f2bf(o0);
  out[base + t + 128] = o1;  outb[base + t + 128] = f2bf(o1);
  out[base + t + 256] = o2;  outb[base + t + 256] = f2bf(o2);
}

__global__ void copy_out(const float* __restrict__ src, float* __restrict__ out) {
  int idx = blockIdx.x * 256 + threadIdx.x;
  if (idx >= BB * TT * DD) return;
  int d = idx % DD;
  int bt = idx / DD;
  int t = bt % TT;
  int b = bt / TT;
  out[idx] = src[((size_t)b * SS + (SS - TT) + t) * DD + d];
}

// ---------------------------------------------------------------------------
extern "C" void kernel_launch(void* const* d_in, const int* in_sizes, int n_in,
                              void* d_out, int out_size, void* d_ws, size_t ws_size,
                              hipStream_t stream) {
  const float* hand_t    = (const float*)d_in[0];
  const float* head_t    = (const float*)d_in[1];
  const float* hand_m1   = (const float*)d_in[2];
  const float* head_m1   = (const float*)d_in[3];
  const float* c_hand_t  = (const float*)d_in[4];
  const float* c_head_t  = (const float*)d_in[5];
  const float* c_hand_m1 = (const float*)d_in[6];
  const float* c_head_m1 = (const float*)d_in[7];
  const float* state_t   = (const float*)d_in[8];
  const float* state_m1  = (const float*)d_in[9];
  const float* tr_t      = (const float*)d_in[10];
  const float* tr_m1     = (const float*)d_in[11];
  const float* tok_m1    = (const float*)d_in[12];
  const float* tok_t     = (const float*)d_in[13];
  const float* Wq = (const float*)d_in[14];
  const float* bq = (const float*)d_in[15];
  const float* Wk = (const float*)d_in[16];
  const float* bk = (const float*)d_in[17];
  const float* Wv = (const float*)d_in[18];
  const float* bv = (const float*)d_in[19];
  const float* Wo = (const float*)d_in[20];
  const float* bo = (const float*)d_in[21];
  const float* W1 = (const float*)d_in[22];
  const float* b1 = (const float*)d_in[23];
  const float* W2 = (const float*)d_in[24];
  const float* b2 = (const float*)d_in[25];
  const float* g1 = (const float*)d_in[26];
  const float* be1 = (const float*)d_in[27];
  const float* g2 = (const float*)d_in[28];
  const float* be2 = (const float*)d_in[29];

  const size_t SRC_N = (size_t)BB * SS * DD;       // 3,176,448
  float* src    = (float*)d_ws;
  float* src2   = src + SRC_N;
  float* bufB   = src2 + SRC_N;
  float* coords = bufB + SRC_N;                    // 24,816
  float* bqkv   = coords + (size_t)BB * SS * 3;    // L*1152
  float2* trig  = (float2*)(bqkv + (size_t)LL * NQKV);   // B*S*24 float2
  u16* srcb  = (u16*)(trig + (size_t)BB * SS * 24);
  u16* src2b = srcb + SRC_N;
  u16* attnb = src2b + SRC_N;
  u16* qh  = attnb + SRC_N;
  const size_t QH_N = (size_t)BB * HH * SS * 64;   // 4,233,216
  u16* khb = qh + QH_N;
  u16* vtb = khb + QH_N;                           // 64*48*1088
  u16* hbf = vtb + (size_t)64 * DH * SSP;          // 12,705,792
  u16* wqkv_b = hbf + (size_t)MROWS * FFD;
  const size_t WD = (size_t)LL * DD * DD;
  const size_t WF = (size_t)LL * FFD * DD;
  u16* wo_bf = wqkv_b + (size_t)LL * NQKV * 384;
  u16* w1_bf = wo_bf + WD;
  u16* w2_bf = w1_bf + WF;

  const int M = MROWS;
  dim3 blk(256);

  build_src<<<(BB * SS * DD + 255) / 256, blk, 0, stream>>>(
      hand_t, head_t, hand_m1, head_m1, state_t, state_m1, tok_m1, tok_t, src, srcb);
  build_coords<<<(BB * SS * 3 + 255) / 256, blk, 0, stream>>>(
      c_hand_t, c_head_t, c_hand_m1, c_head_m1, tr_t, tr_m1, coords);
  build_trig<<<(BB * SS * 24 + 255) / 256, blk, 0, stream>>>(coords, trig);
  pack_qkv<<<(LL * NQKV * 96 + 255) / 256, blk, 0, stream>>>(Wq, Wk, Wv, wqkv_b);
  pack_bqkv<<<(LL * NQKV + 255) / 256, blk, 0, stream>>>(bq, bk, bv, bqkv);
  cvt_bf<<<(int)(WD / 4 + 255) / 256, blk, 0, stream>>>(Wo, wo_bf, (int)(WD / 4));
  cvt_bf<<<(int)(WF / 4 + 255) / 256, blk, 0, stream>>>(W1, w1_bf, (int)(WF / 4));
  cvt_bf<<<(int)(WF / 4 + 255) / 256, blk, 0, stream>>>(W2, w2_bf, (int)(WF / 4));
  pad_vt<<<(64 * DH * (SSP - SS) + 255) / 256, blk, 0, stream>>>(vtb);
  pad_qk<<<(64 * SS * 16 + 255) / 256, blk, 0, stream>>>(qh, khb);

  dim3 gq(DD / 64, (M + 127) / 128);       // (6, 65)
  dim3 gqkv(NQKV / 64, (M + 127) / 128);   // (18, 65)
  dim3 gf1(FFD / 64, (M + 127) / 128);     // (24, 65)
  dim3 gattn(17 * 8 * 8);                  // 1-D, XCD-grouped in-kernel

  for (int l = 0; l < LL; ++l) {
    const u16* Wqkv_l = wqkv_b + (size_t)l * NQKV * 384;
    const u16* Wo_l = wo_bf + (size_t)l * DD * DD;
    const u16* W1_l = w1_bf + (size_t)l * FFD * DD;
    const u16* W2_l = w2_bf + (size_t)l * DD * FFD;

    gemm_as<0, 2><<<gqkv, blk, 0, stream>>>(srcb, Wqkv_l, bqkv + l * NQKV, trig,
                                            nullptr, qh, khb, vtb, M, NQKV, DD);
    attn_mfma<<<gattn, blk, 0, stream>>>(qh, khb, vtb, attnb);
    gemm_as<0, 0><<<gq, blk, 0, stream>>>(attnb, Wo_l, bo + l * DD, nullptr,
                                          bufB, nullptr, nullptr, nullptr, M, DD, DD);
    add_ln<<<M, 128, 0, stream>>>(src, bufB, g1 + l * DD, be1 + l * DD, src2, src2b);
    gemm_as<1, 1><<<gf1, blk, 0, stream>>>(src2b, W1_l, b1 + l * FFD, nullptr,
                                           nullptr, hbf, nullptr, nullptr, M, FFD, DD);
    gemm_as<0, 0><<<gq, blk, 0, stream>>>(hbf, W2_l, b2 + l * DD, nullptr,
                                          bufB, nullptr, nullptr, nullptr, M, DD, FFD);
    add_ln<<<M, 128, 0, stream>>>(src2, bufB, g2 + l * DD, be2 + l * DD, src, srcb);
  }
  copy_out<<<(BB * TT * DD + 255) / 256, blk, 0, stream>>>(src, (float*)d_out);
}

// Round 7
// 1128.165 us; speedup vs baseline: 1.3383x; 1.0495x over previous
//
#include <hip/hip_runtime.h>
#include <hip/hip_bf16.h>
#include <math.h>

#define BB 8
#define NN 256
#define DD 384
#define LL 6
#define HH 8
#define FFD 1536
#define TT 4
#define DH 48
#define NM1 517      // T + 1 + 2N
#define SS 1034      // 2 * NM1
#define SSP 1088     // padded key stride for vt (17*64)
#define MROWS (BB*SS)
#define NQKV 1152
#define QSCALE 0.14433756729740643f

typedef unsigned short u16;
typedef unsigned int u32;
typedef short bf8 __attribute__((ext_vector_type(8)));
typedef float f32x4 __attribute__((ext_vector_type(4)));

__device__ __forceinline__ u16 f2bf(float f) {
  __hip_bfloat16 h = __float2bfloat16(f);
  return *reinterpret_cast<u16*>(&h);
}
__device__ __forceinline__ float bf2f(u16 u) {
  __hip_bfloat16 h;
  *reinterpret_cast<u16*>(&h) = u;
  return __bfloat162float(h);
}
// async global->LDS, 16B per lane; lds dest wave-uniform (HW adds lane*16)
__device__ __forceinline__ void async16(void* lds, const void* g) {
  __builtin_amdgcn_global_load_lds(
      (const __attribute__((address_space(1))) unsigned int*)g,
      (__attribute__((address_space(3))) unsigned int*)lds, 16, 0, 0);
}

// ---------------------------------------------------------------------------
// src assembly: fp32 residual + bf16 mirror.
// ---------------------------------------------------------------------------
__global__ void build_src(const float* __restrict__ hand_t, const float* __restrict__ head_t,
                          const float* __restrict__ hand_m1, const float* __restrict__ head_m1,
                          const float* __restrict__ state_t, const float* __restrict__ state_m1,
                          const float* __restrict__ tok_m1, const float* __restrict__ tok_t,
                          float* __restrict__ src, u16* __restrict__ srcb) {
  int idx = blockIdx.x * 256 + threadIdx.x;
  if (idx >= BB * SS * DD) return;
  int d = idx % DD;
  int bs = idx / DD;
  int s = bs % SS;
  int b = bs / SS;
  float val;
  if (s == 0)               val = state_m1[b * DD + d];
  else if (s <= NN)         val = hand_m1[((size_t)(b * NN + (s - 1))) * DD + d];
  else if (s <= 2 * NN)     val = head_m1[((size_t)(b * NN + (s - 1 - NN))) * DD + d];
  else if (s <= 2 * NN + TT) val = tok_m1[(s - (2 * NN + 1)) * DD + d];
  else if (s == NM1)        val = state_t[b * DD + d];
  else if (s <= NM1 + NN)   val = hand_t[((size_t)(b * NN + (s - NM1 - 1))) * DD + d];
  else if (s <= NM1 + 2 * NN) val = head_t[((size_t)(b * NN + (s - NM1 - 1 - NN))) * DD + d];
  else                      val = tok_t[(s - (NM1 + 2 * NN + 1)) * DD + d];
  src[idx] = val;
  srcb[idx] = f2bf(val);
}

__global__ void build_coords(const float* __restrict__ c_hand_t, const float* __restrict__ c_head_t,
                             const float* __restrict__ c_hand_m1, const float* __restrict__ c_head_m1,
                             const float* __restrict__ tr_t, const float* __restrict__ tr_m1,
                             float* __restrict__ coords) {
  int idx = blockIdx.x * 256 + threadIdx.x;
  if (idx >= BB * SS * 3) return;
  int a = idx % 3;
  int bs = idx / 3;
  int s = bs % SS;
  int b = bs / SS;
  float val;
  if (s == 0)               val = tr_m1[b * 3 + a];
  else if (s <= NN)         val = c_hand_m1[(b * NN + (s - 1)) * 3 + a];
  else if (s <= 2 * NN)     val = c_head_m1[(b * NN + (s - 1 - NN)) * 3 + a];
  else if (s <= 2 * NN + TT) val = tr_m1[b * 3 + a];
  else if (s == NM1)        val = tr_t[b * 3 + a];
  else if (s <= NM1 + NN)   val = c_hand_t[(b * NN + (s - NM1 - 1)) * 3 + a];
  else if (s <= NM1 + 2 * NN) val = c_head_t[(b * NN + (s - NM1 - 1 - NN)) * 3 + a];
  else                      val = tr_t[b * 3 + a];
  coords[idx] = val;
}

// cos/sin table: trig[(b*SS+s)*24 + axis*8 + i] = {cos, sin}(coords*inv_freq)
__global__ void build_trig(const float* __restrict__ coords, float2* __restrict__ trig) {
  int idx = blockIdx.x * 256 + threadIdx.x;
  if (idx >= BB * SS * 24) return;
  int i = idx & 7;
  int axis = (idx >> 3) % 3;
  int bs = idx / 24;
  float cv = coords[bs * 3 + axis];
  float inv = expf(-(float)i * 1.1512925464970229f);  // 10000^(-i/8)
  float ang = cv * inv;
  trig[idx] = make_float2(cosf(ang), sinf(ang));
}

// ---------------------------------------------------------------------------
// weight conversion / packing
// ---------------------------------------------------------------------------
__global__ void cvt_bf(const float* __restrict__ in, u16* __restrict__ out, int n4) {
  int idx = blockIdx.x * 256 + threadIdx.x;
  if (idx >= n4) return;
  float4 v = reinterpret_cast<const float4*>(in)[idx];
  short4 o;
  o.x = (short)f2bf(v.x); o.y = (short)f2bf(v.y);
  o.z = (short)f2bf(v.z); o.w = (short)f2bf(v.w);
  reinterpret_cast<short4*>(out)[idx] = o;
}

__global__ void pack_qkv(const float* __restrict__ Wq, const float* __restrict__ Wk,
                         const float* __restrict__ Wv, u16* __restrict__ wqkv) {
  int idx = blockIdx.x * 256 + threadIdx.x;
  const int TOTAL = LL * NQKV * 96;
  if (idx >= TOTAL) return;
  int k4 = idx % 96;
  int n = (idx / 96) % NQKV;
  int l = idx / (96 * NQKV);
  int sel = n / 384, nn = n - sel * 384;
  const float* W = (sel == 0) ? Wq : ((sel == 1) ? Wk : Wv);
  float4 v = *reinterpret_cast<const float4*>(W + ((size_t)l * 384 + nn) * 384 + k4 * 4);
  short4 o;
  o.x = (short)f2bf(v.x); o.y = (short)f2bf(v.y);
  o.z = (short)f2bf(v.z); o.w = (short)f2bf(v.w);
  *reinterpret_cast<short4*>(wqkv + ((size_t)(l * NQKV + n) * 384 + k4 * 4)) = o;
}

__global__ void pack_bqkv(const float* __restrict__ bq, const float* __restrict__ bk,
                          const float* __restrict__ bv, float* __restrict__ bqkv) {
  int idx = blockIdx.x * 256 + threadIdx.x;
  if (idx >= LL * NQKV) return;
  int n = idx % NQKV, l = idx / NQKV;
  int sel = n / 384, nn = n - sel * 384;
  const float* Bp = (sel == 0) ? bq : ((sel == 1) ? bk : bv);
  bqkv[idx] = Bp[l * 384 + nn];
}

// zero the padded key columns [SS, SSP) of vt
__global__ void pad_vt(u16* __restrict__ vt) {
  int idx = blockIdx.x * 256 + threadIdx.x;
  const int PADW = SSP - SS;
  if (idx >= 64 * DH * PADW) return;
  int c = idx % PADW;
  int rd = idx / PADW;
  vt[(size_t)rd * SSP + SS + c] = 0;
}

// zero the d=48..63 pad of qh/kh (GEMM epilogue writes only d<48)
__global__ void pad_qk(u16* __restrict__ qh, u16* __restrict__ kh) {
  int idx = blockIdx.x * 256 + threadIdx.x;
  if (idx >= 64 * SS * 16) return;
  int c = idx & 15;
  int row = idx >> 4;
  qh[(size_t)row * 64 + 48 + c] = 0;
  kh[(size_t)row * 64 + 48 + c] = 0;
}

// ---------------------------------------------------------------------------
// MFMA GEMM, bf16 in, async global->LDS staging, 2-phase double-buffered with
// COUNTED vmcnt: stage(t+1) stays in flight across compute(t).
//   C[m,n] = sum_k A[m,k]*W[n,k] + bias[n]
//   EPI: 0 none, 1 exact GELU.
//   OUT: 0 fp32 row-major, 1 bf16 row-major, 2 fused-QKV routing WITH RoPE.
// Tile 128x64, BK=64, 4 waves (2x2).
// ---------------------------------------------------------------------------
template <int EPI, int OUT>
__global__ __launch_bounds__(256) void gemm_as(
    const u16* __restrict__ Ab, const u16* __restrict__ Wb,
    const float* __restrict__ bias, const float2* __restrict__ trig,
    float* __restrict__ Cf, u16* __restrict__ Cb,
    u16* __restrict__ Ck, u16* __restrict__ Cv,
    int M, int N, int K) {
  __shared__ __align__(16) char sm[49152];  // 2 x (A 16KB + B 8KB)
  const int tid = threadIdx.x;
  const int bm = blockIdx.y * 128, bn = blockIdx.x * 64;
  const int lid = tid & 63, w = tid >> 6;
  const int wm = w >> 1, wn = w & 1;
  const int l15 = lid & 15, lg = lid >> 4;
  const int lr = lid >> 3, lu = lid & 7;
  const int swz = lu ^ lr;
  f32x4 acc[4][2] = {};

  auto stage = [&](int bsel, int k0) {
    char* base = sm + bsel * 24576;
#pragma unroll
    for (int q = 0; q < 4; ++q) {
      int row = w * 32 + q * 8 + lr;
      int grow = bm + row; if (grow >= M) grow = M - 1;
      async16(base + w * 4096 + q * 1024, Ab + (size_t)grow * K + k0 + (swz << 3));
    }
#pragma unroll
    for (int q = 0; q < 2; ++q) {
      int row = w * 16 + q * 8 + lr;
      async16(base + 16384 + w * 2048 + q * 1024, Wb + (size_t)(bn + row) * K + k0 + (swz << 3));
    }
  };

  stage(0, 0);   // 6 loads in flight
  int bs = 0;

  for (int k0 = 0; k0 < K; k0 += 64) {
    if (k0 + 64 < K) {
      stage(bs ^ 1, k0 + 64);                           // +6 loads for t+1
      asm volatile("s_waitcnt vmcnt(6)" ::: "memory");  // tile t landed; t+1 in flight
    } else {
      asm volatile("s_waitcnt vmcnt(0)" ::: "memory");
    }
    __builtin_amdgcn_s_barrier();                       // all waves' tile t visible
    const char* base = sm + bs * 24576;
    bf8 a[2][4], bfr[2][2];
#pragma unroll
    for (int kf = 0; kf < 2; ++kf) {
#pragma unroll
      for (int mt = 0; mt < 4; ++mt) {
        int row = wm * 64 + mt * 16 + l15;
        int off = ((row << 7) + (kf << 6) + (lg << 4)) ^ ((row & 7) << 4);
        a[kf][mt] = *reinterpret_cast<const bf8*>(base + off);
      }
#pragma unroll
      for (int nt = 0; nt < 2; ++nt) {
        int row = wn * 32 + nt * 16 + l15;
        int off = 16384 + (((row << 7) + (kf << 6) + (lg << 4)) ^ ((row & 7) << 4));
        bfr[kf][nt] = *reinterpret_cast<const bf8*>(base + off);
      }
    }
#pragma unroll
    for (int kf = 0; kf < 2; ++kf)
#pragma unroll
      for (int mt = 0; mt < 4; ++mt)
#pragma unroll
        for (int nt = 0; nt < 2; ++nt)
          acc[mt][nt] = __builtin_amdgcn_mfma_f32_16x16x32_bf16(a[kf][mt], bfr[kf][nt], acc[mt][nt], 0, 0, 0);
    asm volatile("s_waitcnt lgkmcnt(0)" ::: "memory");  // all LDS reads of buf bs done
    __builtin_amdgcn_s_barrier();                       // WAR: buf bs free for next stage
    bs ^= 1;
  }

#pragma unroll
  for (int nt = 0; nt < 2; ++nt) {
    const int n = bn + wn * 32 + nt * 16 + l15;
    const float bsv = bias[n];
#pragma unroll
    for (int mt = 0; mt < 4; ++mt) {
      const int m0 = bm + wm * 64 + mt * 16 + lg * 4;
      if (OUT != 2) {
#pragma unroll
        for (int r = 0; r < 4; ++r) {
          int m = m0 + r;
          if (m >= M) continue;
          float v = acc[mt][nt][r] + bsv;
          if (EPI == 1) v = 0.5f * v * (1.0f + erff(v * 0.70710678118654752f));
          if (OUT == 0) Cf[(size_t)m * N + n] = v;
          else          Cb[(size_t)m * N + n] = f2bf(v);
        }
      } else {
        const int sel = n / 384, nn = n - sel * 384;
        const int hdiv = nn / DH, hrem = nn - hdiv * DH;
        const int axis = hrem >> 4, ii = l15 & 7;
        const bool lo = (l15 & 8) == 0;
#pragma unroll
        for (int r = 0; r < 4; ++r) {
          int m = m0 + r;
          int mc = (m < M) ? m : (M - 1);
          float v = acc[mt][nt][r] + bsv;
          float p = __shfl_xor(v, 8);  // rotation partner (d +/- 8)
          int bI = mc / SS, s = mc - bI * SS;
          float outv;
          if (sel < 2) {
            float2 t = trig[(size_t)(bI * SS + s) * 24 + axis * 8 + ii];
            outv = lo ? (v * t.x - p * t.y) : (p * t.y + v * t.x);
            if (sel == 0) outv *= QSCALE;
          } else {
            outv = v;
          }
          if (m < M) {
            int bh = bI * HH + hdiv;
            if (sel == 0)      Cb[((size_t)bh * SS + s) * 64 + hrem] = f2bf(outv);
            else if (sel == 1) Ck[((size_t)bh * SS + s) * 64 + hrem] = f2bf(outv);
            else               Cv[((size_t)bh * DH + hrem) * SSP + s] = f2bf(outv);
          }
        }
      }
    }
  }
}

// ---------------------------------------------------------------------------
// Flash attention v6: swapped QK^T + PERMUTED K staging so P needs NO
// cross-lane redistribution. K-tile LDS row s holds global key j0 + pi(s),
// pi(s) = (jt>>1)*32 + lg*8 + (jt&1)*4 + r  (s = jt*16 + lg*4 + r, bijective).
// Then lane's sv[jt][r] are exactly its PV A-fragment entries:
//   pa[jc][i] = pv[jc*2 + (i>>2)][i&3]   (pure in-lane pack, zero shuffles).
// V stays natural order; mask computes absolute key through pi.
// ---------------------------------------------------------------------------
__global__ __launch_bounds__(256) void attn_mfma(const u16* __restrict__ qh,
                                                 const u16* __restrict__ kh,
                                                 const u16* __restrict__ vt,
                                                 u16* __restrict__ outb) {
  // buf b: K 8KB @ b*14336, Vt 6KB @ b*14336+8192
  __shared__ __align__(16) char sm[28672];
  const int tid = threadIdx.x;
  const int lid = tid & 63, w = tid >> 6;
  const int l15 = lid & 15, lg = lid >> 4;
  const int lr = lid >> 3, lu = lid & 7;
  const int swz8 = (lu ^ lr) << 3;

  // XCD-grouped remap: f = low(3b: xcd) + 8*( gi*17 + qp17 )
  const int f = blockIdx.x;
  const int low = f & 7, j = f >> 3;
  const int gi = j / 17, qp17 = j - gi * 17;
  const int g = gi * 8 + low;          // (b,h) group
  const int h = g & 7, b = g >> 3;
  const int qblk = 16 - qp17;          // long (17-chunk) blocks first
  const int bh = b * HH + h;
  const int q0w = qblk * 64 + w * 16;
  const u16* kbase = kh + (size_t)bh * SS * 64;
  const u16* vbase = vt + (size_t)bh * DH * SSP;

  bf8 qf[2];
  {
    int row = q0w + l15; if (row >= SS) row = SS - 1;
    const u16* qp = qh + ((size_t)bh * SS + row) * 64;
    qf[0] = *reinterpret_cast<const bf8*>(qp + lg * 8);
    qf[1] = *reinterpret_cast<const bf8*>(qp + 32 + lg * 8);
  }
  const int qrow = q0w + l15;   // this lane's query (for mask + softmax state)

  float m_q = -1e30f, l_q = 0.f;
  f32x4 accO[3] = {};

  const int nch = (qblk < 8) ? 9 : 17;

  auto stage = [&](int bsel, int c) {
    const int j0 = c * 64;
    char* kb = sm + bsel * 14336;
    char* vb = kb + 8192;
#pragma unroll
    for (int qq = 0; qq < 2; ++qq) {
      int is = w * 2 + qq;
      int s = is * 8 + lr;                       // LDS row
      int jt_ = s >> 4, lgs = (s >> 2) & 3, rr = s & 3;
      int p = ((jt_ >> 1) << 5) + (lgs << 3) + ((jt_ & 1) << 2) + rr;  // pi(s)
      int jrow = j0 + p; if (jrow >= SS) jrow = SS - 1;
      async16(kb + is * 1024, kbase + (size_t)jrow * 64 + swz8);
    }
    async16(vb + w * 1024, vbase + (size_t)(w * 8 + lr) * SSP + j0 + swz8);
    if (w < 2)
      async16(vb + (4 + w) * 1024, vbase + (size_t)((4 + w) * 8 + lr) * SSP + j0 + swz8);
  };

  stage(0, 0);
  __syncthreads();
  int bsel = 0;

  for (int c = 0; c < nch; ++c) {
    if (c + 1 < nch) stage(bsel ^ 1, c + 1);
    const int j0 = c * 64;
    const char* kb = sm + bsel * 14336;
    const char* vb = kb + 8192;

    // QK^T swapped: sv[jt][r] = S[pi-slot = jt*16+lg*4+r][q = l15]
    f32x4 sv[4];
#pragma unroll
    for (int jt = 0; jt < 4; ++jt) {
      int row = jt * 16 + l15;
      int off0 = ((row << 7) + (lg << 4)) ^ ((row & 7) << 4);
      int off1 = ((row << 7) + 64 + (lg << 4)) ^ ((row & 7) << 4);
      bf8 kb0 = *reinterpret_cast<const bf8*>(kb + off0);
      bf8 kb1 = *reinterpret_cast<const bf8*>(kb + off1);
      f32x4 z = {};
      z = __builtin_amdgcn_mfma_f32_16x16x32_bf16(kb0, qf[0], z, 0, 0, 0);
      z = __builtin_amdgcn_mfma_f32_16x16x32_bf16(kb1, qf[1], z, 0, 0, 0);
      sv[jt] = z;
    }

    const bool domask = (c == 16) | ((q0w < NM1) & (c >= 8));
    if (domask) {
#pragma unroll
      for (int jt = 0; jt < 4; ++jt)
#pragma unroll
        for (int r = 0; r < 4; ++r) {
          // absolute key of slot (jt,lg,r) is j0 + pi(slot)
          int kabs = j0 + ((jt >> 1) << 5) + (lg << 3) + ((jt & 1) << 2) + r;
          if (kabs >= SS || (qrow < NM1 && kabs >= NM1)) sv[jt][r] = -1e30f;
        }
    }

    // row max: 16 in-register + 2 cross-group shfl
    float mx = sv[0][0];
#pragma unroll
    for (int jt = 0; jt < 4; ++jt)
#pragma unroll
      for (int r = 0; r < 4; ++r) mx = fmaxf(mx, sv[jt][r]);
    mx = fmaxf(mx, __shfl_xor(mx, 16));
    mx = fmaxf(mx, __shfl_xor(mx, 32));

    const bool skip = __all(mx <= m_q);   // T13: no new max anywhere -> no rescale
    const float mn = skip ? m_q : fmaxf(m_q, mx);

    float pv[4][4];
    float ps = 0.f;
#pragma unroll
    for (int jt = 0; jt < 4; ++jt)
#pragma unroll
      for (int r = 0; r < 4; ++r) {
        float p = __expf(sv[jt][r] - mn);
        pv[jt][r] = p;
        ps += p;
      }
    ps += __shfl_xor(ps, 16);
    ps += __shfl_xor(ps, 32);

    if (!skip) {
      float alpha = __expf(m_q - mn);
      l_q = l_q * alpha + ps;
      m_q = mn;
      const int lg4 = lg * 4;
      float a0 = __shfl(alpha, lg4);
      float a1 = __shfl(alpha, lg4 + 1);
      float a2 = __shfl(alpha, lg4 + 2);
      float a3 = __shfl(alpha, lg4 + 3);
#pragma unroll
      for (int dt = 0; dt < 3; ++dt) {
        accO[dt][0] *= a0; accO[dt][1] *= a1;
        accO[dt][2] *= a2; accO[dt][3] *= a3;
      }
    } else {
      l_q += ps;
    }

    // pa[jc][i] = pv[jc*2 + (i>>2)][i&3] -- pure in-lane bf16 pack
    bf8 pa[2];
#pragma unroll
    for (int jc = 0; jc < 2; ++jc) {
      u32 w0 = (u32)f2bf(pv[jc * 2][0])     | ((u32)f2bf(pv[jc * 2][1]) << 16);
      u32 w1 = (u32)f2bf(pv[jc * 2][2])     | ((u32)f2bf(pv[jc * 2][3]) << 16);
      u32 w2 = (u32)f2bf(pv[jc * 2 + 1][0]) | ((u32)f2bf(pv[jc * 2 + 1][1]) << 16);
      u32 w3 = (u32)f2bf(pv[jc * 2 + 1][2]) | ((u32)f2bf(pv[jc * 2 + 1][3]) << 16);
      uint4 t = make_uint4(w0, w1, w2, w3);
      pa[jc] = *reinterpret_cast<bf8*>(&t);
    }

    // PV from LDS Vt tile (natural key order matches pi via construction)
#pragma unroll
    for (int dt = 0; dt < 3; ++dt) {
      int row = dt * 16 + l15;
#pragma unroll
      for (int jc = 0; jc < 2; ++jc) {
        int off = ((row << 7) + (jc << 6) + (lg << 4)) ^ ((row & 7) << 4);
        bf8 vb8 = *reinterpret_cast<const bf8*>(vb + off);
        accO[dt] = __builtin_amdgcn_mfma_f32_16x16x32_bf16(pa[jc], vb8, accO[dt], 0, 0, 0);
      }
    }
    __syncthreads();  // drains vmcnt (c+1 staged) + frees buf for c+2
    bsel ^= 1;
  }

  // epilogue: fetch 1/l for the 4 output rows (q = q0w + lg*4 + r)
  float linv = 1.0f / l_q;
  const int lg4 = lg * 4;
  float il[4];
#pragma unroll
  for (int r = 0; r < 4; ++r) il[r] = __shfl(linv, lg4 + r);
#pragma unroll
  for (int r = 0; r < 4; ++r) {
    int q = q0w + lg4 + r;
    if (q >= SS) continue;
#pragma unroll
    for (int dt = 0; dt < 3; ++dt) {
      int d = dt * 16 + l15;
      outb[((size_t)(b * SS + q)) * DD + h * DH + d] = f2bf(accO[dt][r] * il[r]);
    }
  }
}

// ---------------------------------------------------------------------------
// out = LayerNorm(a + r) * g + be, fp32 + bf16 mirror.
// ---------------------------------------------------------------------------
__global__ __launch_bounds__(128) void add_ln(const float* __restrict__ a,
                                              const float* __restrict__ r,
                                              const float* __restrict__ g,
                                              const float* __restrict__ be,
                                              float* __restrict__ out,
                                              u16* __restrict__ outb) {
  __shared__ float p1[2], p2[2];
  const int row = blockIdx.x;
  const int t = threadIdx.x;
  const size_t base = (size_t)row * DD;
  float x0 = a[base + t] + r[base + t];
  float x1 = a[base + t + 128] + r[base + t + 128];
  float x2 = a[base + t + 256] + r[base + t + 256];
  float s = x0 + x1 + x2;
#pragma unroll
  for (int off = 32; off; off >>= 1) s += __shfl_xor(s, off);
  if ((t & 63) == 0) p1[t >> 6] = s;
  __syncthreads();
  float mean = (p1[0] + p1[1]) * (1.0f / 384.0f);
  float d0 = x0 - mean, d1 = x1 - mean, d2 = x2 - mean;
  float vsum = d0 * d0 + d1 * d1 + d2 * d2;
#pragma unroll
  for (int off = 32; off; off >>= 1) vsum += __shfl_xor(vsum, off);
  if ((t & 63) == 0) p2[t >> 6] = vsum;
  __syncthreads();
  float var = (p2[0] + p2[1]) * (1.0f / 384.0f);
  float rs = rsqrtf(var + 1e-5f);
  float o0 = d0 * rs * g[t]       + be[t];
  float o1 = d1 * rs * g[t + 128] + be[t + 128];
  float o2 = d2 * rs * g[t + 256] + be[t + 256];
  out[base + t] = o0;        outb[base + t] = f2bf(o0);
  out[base + t + 128] = o1;  outb[base + t + 128] = f2bf(o1);
  out[base + t + 256] = o2;  outb[base + t + 256] = f2bf(o2);
}

__global__ void copy_out(const float* __restrict__ src, float* __restrict__ out) {
  int idx = blockIdx.x * 256 + threadIdx.x;
  if (idx >= BB * TT * DD) return;
  int d = idx % DD;
  int bt = idx / DD;
  int t = bt % TT;
  int b = bt / TT;
  out[idx] = src[((size_t)b * SS + (SS - TT) + t) * DD + d];
}

// ---------------------------------------------------------------------------
extern "C" void kernel_launch(void* const* d_in, const int* in_sizes, int n_in,
                              void* d_out, int out_size, void* d_ws, size_t ws_size,
                              hipStream_t stream) {
  const float* hand_t    = (const float*)d_in[0];
  const float* head_t    = (const float*)d_in[1];
  const float* hand_m1   = (const float*)d_in[2];
  const float* head_m1   = (const float*)d_in[3];
  const float* c_hand_t  = (const float*)d_in[4];
  const float* c_head_t  = (const float*)d_in[5];
  const float* c_hand_m1 = (const float*)d_in[6];
  const float* c_head_m1 = (const float*)d_in[7];
  const float* state_t   = (const float*)d_in[8];
  const float* state_m1  = (const float*)d_in[9];
  const float* tr_t      = (const float*)d_in[10];
  const float* tr_m1     = (const float*)d_in[11];
  const float* tok_m1    = (const float*)d_in[12];
  const float* tok_t     = (const float*)d_in[13];
  const float* Wq = (const float*)d_in[14];
  const float* bq = (const float*)d_in[15];
  const float* Wk = (const float*)d_in[16];
  const float* bk = (const float*)d_in[17];
  const float* Wv = (const float*)d_in[18];
  const float* bv = (const float*)d_in[19];
  const float* Wo = (const float*)d_in[20];
  const float* bo = (const float*)d_in[21];
  const float* W1 = (const float*)d_in[22];
  const float* b1 = (const float*)d_in[23];
  const float* W2 = (const float*)d_in[24];
  const float* b2 = (const float*)d_in[25];
  const float* g1 = (const float*)d_in[26];
  const float* be1 = (const float*)d_in[27];
  const float* g2 = (const float*)d_in[28];
  const float* be2 = (const float*)d_in[29];

  const size_t SRC_N = (size_t)BB * SS * DD;       // 3,176,448
  float* src    = (float*)d_ws;
  float* src2   = src + SRC_N;
  float* bufB   = src2 + SRC_N;
  float* coords = bufB + SRC_N;                    // 24,816
  float* bqkv   = coords + (size_t)BB * SS * 3;    // L*1152
  float2* trig  = (float2*)(bqkv + (size_t)LL * NQKV);   // B*S*24 float2
  u16* srcb  = (u16*)(trig + (size_t)BB * SS * 24);
  u16* src2b = srcb + SRC_N;
  u16* attnb = src2b + SRC_N;
  u16* qh  = attnb + SRC_N;
  const size_t QH_N = (size_t)BB * HH * SS * 64;   // 4,233,216
  u16* khb = qh + QH_N;
  u16* vtb = khb + QH_N;                           // 64*48*1088
  u16* hbf = vtb + (size_t)64 * DH * SSP;          // 12,705,792
  u16* wqkv_b = hbf + (size_t)MROWS * FFD;
  const size_t WD = (size_t)LL * DD * DD;
  const size_t WF = (size_t)LL * FFD * DD;
  u16* wo_bf = wqkv_b + (size_t)LL * NQKV * 384;
  u16* w1_bf = wo_bf + WD;
  u16* w2_bf = w1_bf + WF;

  const int M = MROWS;
  dim3 blk(256);

  build_src<<<(BB * SS * DD + 255) / 256, blk, 0, stream>>>(
      hand_t, head_t, hand_m1, head_m1, state_t, state_m1, tok_m1, tok_t, src, srcb);
  build_coords<<<(BB * SS * 3 + 255) / 256, blk, 0, stream>>>(
      c_hand_t, c_head_t, c_hand_m1, c_head_m1, tr_t, tr_m1, coords);
  build_trig<<<(BB * SS * 24 + 255) / 256, blk, 0, stream>>>(coords, trig);
  pack_qkv<<<(LL * NQKV * 96 + 255) / 256, blk, 0, stream>>>(Wq, Wk, Wv, wqkv_b);
  pack_bqkv<<<(LL * NQKV + 255) / 256, blk, 0, stream>>>(bq, bk, bv, bqkv);
  cvt_bf<<<(int)(WD / 4 + 255) / 256, blk, 0, stream>>>(Wo, wo_bf, (int)(WD / 4));
  cvt_bf<<<(int)(WF / 4 + 255) / 256, blk, 0, stream>>>(W1, w1_bf, (int)(WF / 4));
  cvt_bf<<<(int)(WF / 4 + 255) / 256, blk, 0, stream>>>(W2, w2_bf, (int)(WF / 4));
  pad_vt<<<(64 * DH * (SSP - SS) + 255) / 256, blk, 0, stream>>>(vtb);
  pad_qk<<<(64 * SS * 16 + 255) / 256, blk, 0, stream>>>(qh, khb);

  dim3 gq(DD / 64, (M + 127) / 128);       // (6, 65)
  dim3 gqkv(NQKV / 64, (M + 127) / 128);   // (18, 65)
  dim3 gf1(FFD / 64, (M + 127) / 128);     // (24, 65)
  dim3 gattn(17 * 8 * 8);                  // 1-D, XCD-grouped in-kernel

  for (int l = 0; l < LL; ++l) {
    const u16* Wqkv_l = wqkv_b + (size_t)l * NQKV * 384;
    const u16* Wo_l = wo_bf + (size_t)l * DD * DD;
    const u16* W1_l = w1_bf + (size_t)l * FFD * DD;
    const u16* W2_l = w2_bf + (size_t)l * DD * FFD;

    gemm_as<0, 2><<<gqkv, blk, 0, stream>>>(srcb, Wqkv_l, bqkv + l * NQKV, trig,
                                            nullptr, qh, khb, vtb, M, NQKV, DD);
    attn_mfma<<<gattn, blk, 0, stream>>>(qh, khb, vtb, attnb);
    gemm_as<0, 0><<<gq, blk, 0, stream>>>(attnb, Wo_l, bo + l * DD, nullptr,
                                          bufB, nullptr, nullptr, nullptr, M, DD, DD);
    add_ln<<<M, 128, 0, stream>>>(src, bufB, g1 + l * DD, be1 + l * DD, src2, src2b);
    gemm_as<1, 1><<<gf1, blk, 0, stream>>>(src2b, W1_l, b1 + l * FFD, nullptr,
                                           nullptr, hbf, nullptr, nullptr, M, FFD, DD);
    gemm_as<0, 0><<<gq, blk, 0, stream>>>(hbf, W2_l, b2 + l * DD, nullptr,
                                          bufB, nullptr, nullptr, nullptr, M, DD, FFD);
    add_ln<<<M, 128, 0, stream>>>(src2, bufB, g2 + l * DD, be2 + l * DD, src, srcb);
  }
  copy_out<<<(BB * TT * DD + 255) / 256, blk, 0, stream>>>(src, (float*)d_out);
}

// Round 8
// 1115.426 us; speedup vs baseline: 1.3536x; 1.0114x over previous
//
#include <hip/hip_runtime.h>
#include <hip/hip_bf16.h>
#include <math.h>

#define BB 8
#define NN 256
#define DD 384
#define LL 6
#define HH 8
#define FFD 1536
#define TT 4
#define DH 48
#define NM1 517      // T + 1 + 2N
#define SS 1034      // 2 * NM1
#define SSP 1088     // padded key stride for vt (17*64)
#define MROWS (BB*SS)
#define NQKV 1152
#define QSCALE 0.14433756729740643f

typedef unsigned short u16;
typedef unsigned int u32;
typedef short bf8 __attribute__((ext_vector_type(8)));
typedef float f32x4 __attribute__((ext_vector_type(4)));

__device__ __forceinline__ u16 f2bf(float f) {
  __hip_bfloat16 h = __float2bfloat16(f);
  return *reinterpret_cast<u16*>(&h);
}
__device__ __forceinline__ float bf2f(u16 u) {
  __hip_bfloat16 h;
  *reinterpret_cast<u16*>(&h) = u;
  return __bfloat162float(h);
}
// async global->LDS, 16B per lane; lds dest wave-uniform (HW adds lane*16)
__device__ __forceinline__ void async16(void* lds, const void* g) {
  __builtin_amdgcn_global_load_lds(
      (const __attribute__((address_space(1))) unsigned int*)g,
      (__attribute__((address_space(3))) unsigned int*)lds, 16, 0, 0);
}

// ---------------------------------------------------------------------------
// src assembly: fp32 residual + bf16 mirror.
// ---------------------------------------------------------------------------
__global__ void build_src(const float* __restrict__ hand_t, const float* __restrict__ head_t,
                          const float* __restrict__ hand_m1, const float* __restrict__ head_m1,
                          const float* __restrict__ state_t, const float* __restrict__ state_m1,
                          const float* __restrict__ tok_m1, const float* __restrict__ tok_t,
                          float* __restrict__ src, u16* __restrict__ srcb) {
  int idx = blockIdx.x * 256 + threadIdx.x;
  if (idx >= BB * SS * DD) return;
  int d = idx % DD;
  int bs = idx / DD;
  int s = bs % SS;
  int b = bs / SS;
  float val;
  if (s == 0)               val = state_m1[b * DD + d];
  else if (s <= NN)         val = hand_m1[((size_t)(b * NN + (s - 1))) * DD + d];
  else if (s <= 2 * NN)     val = head_m1[((size_t)(b * NN + (s - 1 - NN))) * DD + d];
  else if (s <= 2 * NN + TT) val = tok_m1[(s - (2 * NN + 1)) * DD + d];
  else if (s == NM1)        val = state_t[b * DD + d];
  else if (s <= NM1 + NN)   val = hand_t[((size_t)(b * NN + (s - NM1 - 1))) * DD + d];
  else if (s <= NM1 + 2 * NN) val = head_t[((size_t)(b * NN + (s - NM1 - 1 - NN))) * DD + d];
  else                      val = tok_t[(s - (NM1 + 2 * NN + 1)) * DD + d];
  src[idx] = val;
  srcb[idx] = f2bf(val);
}

__global__ void build_coords(const float* __restrict__ c_hand_t, const float* __restrict__ c_head_t,
                             const float* __restrict__ c_hand_m1, const float* __restrict__ c_head_m1,
                             const float* __restrict__ tr_t, const float* __restrict__ tr_m1,
                             float* __restrict__ coords) {
  int idx = blockIdx.x * 256 + threadIdx.x;
  if (idx >= BB * SS * 3) return;
  int a = idx % 3;
  int bs = idx / 3;
  int s = bs % SS;
  int b = bs / SS;
  float val;
  if (s == 0)               val = tr_m1[b * 3 + a];
  else if (s <= NN)         val = c_hand_m1[(b * NN + (s - 1)) * 3 + a];
  else if (s <= 2 * NN)     val = c_head_m1[(b * NN + (s - 1 - NN)) * 3 + a];
  else if (s <= 2 * NN + TT) val = tr_m1[b * 3 + a];
  else if (s == NM1)        val = tr_t[b * 3 + a];
  else if (s <= NM1 + NN)   val = c_hand_t[(b * NN + (s - NM1 - 1)) * 3 + a];
  else if (s <= NM1 + 2 * NN) val = c_head_t[(b * NN + (s - NM1 - 1 - NN)) * 3 + a];
  else                      val = tr_t[b * 3 + a];
  coords[idx] = val;
}

// cos/sin table: trig[(b*SS+s)*24 + axis*8 + i] = {cos, sin}(coords*inv_freq)
__global__ void build_trig(const float* __restrict__ coords, float2* __restrict__ trig) {
  int idx = blockIdx.x * 256 + threadIdx.x;
  if (idx >= BB * SS * 24) return;
  int i = idx & 7;
  int axis = (idx >> 3) % 3;
  int bs = idx / 24;
  float cv = coords[bs * 3 + axis];
  float inv = expf(-(float)i * 1.1512925464970229f);  // 10000^(-i/8)
  float ang = cv * inv;
  trig[idx] = make_float2(cosf(ang), sinf(ang));
}

// ---------------------------------------------------------------------------
// weight conversion / packing
// ---------------------------------------------------------------------------
__global__ void cvt_bf(const float* __restrict__ in, u16* __restrict__ out, int n4) {
  int idx = blockIdx.x * 256 + threadIdx.x;
  if (idx >= n4) return;
  float4 v = reinterpret_cast<const float4*>(in)[idx];
  short4 o;
  o.x = (short)f2bf(v.x); o.y = (short)f2bf(v.y);
  o.z = (short)f2bf(v.z); o.w = (short)f2bf(v.w);
  reinterpret_cast<short4*>(out)[idx] = o;
}

__global__ void pack_qkv(const float* __restrict__ Wq, const float* __restrict__ Wk,
                         const float* __restrict__ Wv, u16* __restrict__ wqkv) {
  int idx = blockIdx.x * 256 + threadIdx.x;
  const int TOTAL = LL * NQKV * 96;
  if (idx >= TOTAL) return;
  int k4 = idx % 96;
  int n = (idx / 96) % NQKV;
  int l = idx / (96 * NQKV);
  int sel = n / 384, nn = n - sel * 384;
  const float* W = (sel == 0) ? Wq : ((sel == 1) ? Wk : Wv);
  float4 v = *reinterpret_cast<const float4*>(W + ((size_t)l * 384 + nn) * 384 + k4 * 4);
  short4 o;
  o.x = (short)f2bf(v.x); o.y = (short)f2bf(v.y);
  o.z = (short)f2bf(v.z); o.w = (short)f2bf(v.w);
  *reinterpret_cast<short4*>(wqkv + ((size_t)(l * NQKV + n) * 384 + k4 * 4)) = o;
}

__global__ void pack_bqkv(const float* __restrict__ bq, const float* __restrict__ bk,
                          const float* __restrict__ bv, float* __restrict__ bqkv) {
  int idx = blockIdx.x * 256 + threadIdx.x;
  if (idx >= LL * NQKV) return;
  int n = idx % NQKV, l = idx / NQKV;
  int sel = n / 384, nn = n - sel * 384;
  const float* Bp = (sel == 0) ? bq : ((sel == 1) ? bk : bv);
  bqkv[idx] = Bp[l * 384 + nn];
}

// zero the padded key columns [SS, SSP) of vt
__global__ void pad_vt(u16* __restrict__ vt) {
  int idx = blockIdx.x * 256 + threadIdx.x;
  const int PADW = SSP - SS;
  if (idx >= 64 * DH * PADW) return;
  int c = idx % PADW;
  int rd = idx / PADW;
  vt[(size_t)rd * SSP + SS + c] = 0;
}

// zero the d=48..63 pad of qh/kh (GEMM epilogue writes only d<48)
__global__ void pad_qk(u16* __restrict__ qh, u16* __restrict__ kh) {
  int idx = blockIdx.x * 256 + threadIdx.x;
  if (idx >= 64 * SS * 16) return;
  int c = idx & 15;
  int row = idx >> 4;
  qh[(size_t)row * 64 + 48 + c] = 0;
  kh[(size_t)row * 64 + 48 + c] = 0;
}

// ---------------------------------------------------------------------------
// MFMA GEMM, bf16 in, async global->LDS staging, 2-phase double-buffered with
// COUNTED vmcnt. XCD M-STRIPE mapping: 1-D grid of nxt*72 blocks; g%8 = XCD,
// each XCD owns 9 consecutive M-tiles x all N-tiles (A fetched once per XCD,
// W resident; FFN1-written rows re-read by FFN2 from the SAME XCD L2).
//   C[m,n] = sum_k A[m,k]*W[n,k] + bias[n]  (+ residual Rf for OUT==0)
//   EPI: 0 none, 1 exact GELU.
//   OUT: 0 fp32 row-major (+Rf), 1 bf16 row-major, 2 fused-QKV routing + RoPE.
//   NT:  n-fragments per wave (2 -> 128x64 tile, 4 -> 128x128 tile).
// ---------------------------------------------------------------------------
template <int EPI, int OUT, int NT>
__global__ __launch_bounds__(256) void gemm_as(
    const u16* __restrict__ Ab, const u16* __restrict__ Wb,
    const float* __restrict__ bias, const float2* __restrict__ trig,
    const float* __restrict__ Rf,
    float* __restrict__ Cf, u16* __restrict__ Cb,
    u16* __restrict__ Ck, u16* __restrict__ Cv,
    int M, int N, int K) {
  constexpr int BN = NT * 32;
  constexpr int BUFSZ = 16384 + NT * 4096;
  __shared__ __align__(16) char sm[2 * BUFSZ];
  const int tid = threadIdx.x;

  // XCD M-stripe decomposition
  const int nxt = N / BN;
  const int Mt = (M + 127) >> 7;
  const int gL = blockIdx.x;
  const int x8 = gL & 7, jj = gL >> 3;
  const int mt_ = x8 * 9 + jj / nxt;
  if (mt_ >= Mt) return;
  const int bm = mt_ << 7, bn = (jj % nxt) * BN;

  const int lid = tid & 63, w = tid >> 6;
  const int wm = w >> 1, wn = w & 1;
  const int l15 = lid & 15, lg = lid >> 4;
  const int lr = lid >> 3, lu = lid & 7;
  const int swz = lu ^ lr;
  f32x4 acc[4][NT] = {};

  auto stage = [&](int bsel, int k0) {
    char* base = sm + bsel * BUFSZ;
#pragma unroll
    for (int q = 0; q < 4; ++q) {
      int row = w * 32 + q * 8 + lr;
      int grow = bm + row; if (grow >= M) grow = M - 1;
      async16(base + w * 4096 + q * 1024, Ab + (size_t)grow * K + k0 + (swz << 3));
    }
#pragma unroll
    for (int q = 0; q < NT; ++q) {
      int row = w * (NT * 8) + q * 8 + lr;
      async16(base + 16384 + w * (NT * 1024) + q * 1024,
              Wb + (size_t)(bn + row) * K + k0 + (swz << 3));
    }
  };

  stage(0, 0);   // 4+NT loads in flight per wave
  int bs = 0;

  for (int k0 = 0; k0 < K; k0 += 64) {
    if (k0 + 64 < K) {
      stage(bs ^ 1, k0 + 64);
      if constexpr (NT == 2)
        asm volatile("s_waitcnt vmcnt(6)" ::: "memory");   // tile t landed; t+1 in flight
      else
        asm volatile("s_waitcnt vmcnt(8)" ::: "memory");
    } else {
      asm volatile("s_waitcnt vmcnt(0)" ::: "memory");
    }
    __builtin_amdgcn_s_barrier();                       // all waves' tile t visible
    const char* base = sm + bs * BUFSZ;
    bf8 a[2][4], bfr[2][NT];
#pragma unroll
    for (int kf = 0; kf < 2; ++kf) {
#pragma unroll
      for (int mt = 0; mt < 4; ++mt) {
        int row = wm * 64 + mt * 16 + l15;
        int off = ((row << 7) + (kf << 6) + (lg << 4)) ^ ((row & 7) << 4);
        a[kf][mt] = *reinterpret_cast<const bf8*>(base + off);
      }
#pragma unroll
      for (int nt = 0; nt < NT; ++nt) {
        int row = wn * (NT * 16) + nt * 16 + l15;
        int off = 16384 + (((row << 7) + (kf << 6) + (lg << 4)) ^ ((row & 7) << 4));
        bfr[kf][nt] = *reinterpret_cast<const bf8*>(base + off);
      }
    }
#pragma unroll
    for (int kf = 0; kf < 2; ++kf)
#pragma unroll
      for (int mt = 0; mt < 4; ++mt)
#pragma unroll
        for (int nt = 0; nt < NT; ++nt)
          acc[mt][nt] = __builtin_amdgcn_mfma_f32_16x16x32_bf16(a[kf][mt], bfr[kf][nt], acc[mt][nt], 0, 0, 0);
    asm volatile("s_waitcnt lgkmcnt(0)" ::: "memory");  // all LDS reads of buf bs done
    __builtin_amdgcn_s_barrier();                       // WAR: buf bs free for next stage
    bs ^= 1;
  }

#pragma unroll
  for (int nt = 0; nt < NT; ++nt) {
    const int n = bn + wn * (NT * 16) + nt * 16 + l15;
    const float bsv = bias[n];
#pragma unroll
    for (int mt = 0; mt < 4; ++mt) {
      const int m0 = bm + wm * 64 + mt * 16 + lg * 4;
      if (OUT != 2) {
#pragma unroll
        for (int r = 0; r < 4; ++r) {
          int m = m0 + r;
          if (m >= M) continue;
          float v = acc[mt][nt][r] + bsv;
          if (EPI == 1) v = 0.5f * v * (1.0f + erff(v * 0.70710678118654752f));
          if (OUT == 0) Cf[(size_t)m * N + n] = v + Rf[(size_t)m * N + n];
          else          Cb[(size_t)m * N + n] = f2bf(v);
        }
      } else {
        const int sel = n / 384, nn = n - sel * 384;
        const int hdiv = nn / DH, hrem = nn - hdiv * DH;
        const int axis = hrem >> 4, ii = l15 & 7;
        const bool lo = (l15 & 8) == 0;
#pragma unroll
        for (int r = 0; r < 4; ++r) {
          int m = m0 + r;
          int mc = (m < M) ? m : (M - 1);
          float v = acc[mt][nt][r] + bsv;
          float p = __shfl_xor(v, 8);  // rotation partner (d +/- 8)
          int bI = mc / SS, s = mc - bI * SS;
          float outv;
          if (sel < 2) {
            float2 t = trig[(size_t)(bI * SS + s) * 24 + axis * 8 + ii];
            outv = lo ? (v * t.x - p * t.y) : (p * t.y + v * t.x);
            if (sel == 0) outv *= QSCALE;
          } else {
            outv = v;
          }
          if (m < M) {
            int bh = bI * HH + hdiv;
            if (sel == 0)      Cb[((size_t)bh * SS + s) * 64 + hrem] = f2bf(outv);
            else if (sel == 1) Ck[((size_t)bh * SS + s) * 64 + hrem] = f2bf(outv);
            else               Cv[((size_t)bh * DH + hrem) * SSP + s] = f2bf(outv);
          }
        }
      }
    }
  }
}

// ---------------------------------------------------------------------------
// Flash attention v6: swapped QK^T + PERMUTED K staging so P needs NO
// cross-lane redistribution (see round 6).
// ---------------------------------------------------------------------------
__global__ __launch_bounds__(256) void attn_mfma(const u16* __restrict__ qh,
                                                 const u16* __restrict__ kh,
                                                 const u16* __restrict__ vt,
                                                 u16* __restrict__ outb) {
  // buf b: K 8KB @ b*14336, Vt 6KB @ b*14336+8192
  __shared__ __align__(16) char sm[28672];
  const int tid = threadIdx.x;
  const int lid = tid & 63, w = tid >> 6;
  const int l15 = lid & 15, lg = lid >> 4;
  const int lr = lid >> 3, lu = lid & 7;
  const int swz8 = (lu ^ lr) << 3;

  // XCD-grouped remap: f = low(3b: xcd) + 8*( gi*17 + qp17 )
  const int f = blockIdx.x;
  const int low = f & 7, j = f >> 3;
  const int gi = j / 17, qp17 = j - gi * 17;
  const int g = gi * 8 + low;          // (b,h) group
  const int h = g & 7, b = g >> 3;
  const int qblk = 16 - qp17;          // long (17-chunk) blocks first
  const int bh = b * HH + h;
  const int q0w = qblk * 64 + w * 16;
  const u16* kbase = kh + (size_t)bh * SS * 64;
  const u16* vbase = vt + (size_t)bh * DH * SSP;

  bf8 qf[2];
  {
    int row = q0w + l15; if (row >= SS) row = SS - 1;
    const u16* qp = qh + ((size_t)bh * SS + row) * 64;
    qf[0] = *reinterpret_cast<const bf8*>(qp + lg * 8);
    qf[1] = *reinterpret_cast<const bf8*>(qp + 32 + lg * 8);
  }
  const int qrow = q0w + l15;   // this lane's query (for mask + softmax state)

  float m_q = -1e30f, l_q = 0.f;
  f32x4 accO[3] = {};

  const int nch = (qblk < 8) ? 9 : 17;

  auto stage = [&](int bsel, int c) {
    const int j0 = c * 64;
    char* kb = sm + bsel * 14336;
    char* vb = kb + 8192;
#pragma unroll
    for (int qq = 0; qq < 2; ++qq) {
      int is = w * 2 + qq;
      int s = is * 8 + lr;                       // LDS row
      int jt_ = s >> 4, lgs = (s >> 2) & 3, rr = s & 3;
      int p = ((jt_ >> 1) << 5) + (lgs << 3) + ((jt_ & 1) << 2) + rr;  // pi(s)
      int jrow = j0 + p; if (jrow >= SS) jrow = SS - 1;
      async16(kb + is * 1024, kbase + (size_t)jrow * 64 + swz8);
    }
    async16(vb + w * 1024, vbase + (size_t)(w * 8 + lr) * SSP + j0 + swz8);
    if (w < 2)
      async16(vb + (4 + w) * 1024, vbase + (size_t)((4 + w) * 8 + lr) * SSP + j0 + swz8);
  };

  stage(0, 0);
  __syncthreads();
  int bsel = 0;

  for (int c = 0; c < nch; ++c) {
    if (c + 1 < nch) stage(bsel ^ 1, c + 1);
    const int j0 = c * 64;
    const char* kb = sm + bsel * 14336;
    const char* vb = kb + 8192;

    // QK^T swapped: sv[jt][r] = S[pi-slot = jt*16+lg*4+r][q = l15]
    f32x4 sv[4];
#pragma unroll
    for (int jt = 0; jt < 4; ++jt) {
      int row = jt * 16 + l15;
      int off0 = ((row << 7) + (lg << 4)) ^ ((row & 7) << 4);
      int off1 = ((row << 7) + 64 + (lg << 4)) ^ ((row & 7) << 4);
      bf8 kb0 = *reinterpret_cast<const bf8*>(kb + off0);
      bf8 kb1 = *reinterpret_cast<const bf8*>(kb + off1);
      f32x4 z = {};
      z = __builtin_amdgcn_mfma_f32_16x16x32_bf16(kb0, qf[0], z, 0, 0, 0);
      z = __builtin_amdgcn_mfma_f32_16x16x32_bf16(kb1, qf[1], z, 0, 0, 0);
      sv[jt] = z;
    }

    const bool domask = (c == 16) | ((q0w < NM1) & (c >= 8));
    if (domask) {
#pragma unroll
      for (int jt = 0; jt < 4; ++jt)
#pragma unroll
        for (int r = 0; r < 4; ++r) {
          // absolute key of slot (jt,lg,r) is j0 + pi(slot)
          int kabs = j0 + ((jt >> 1) << 5) + (lg << 3) + ((jt & 1) << 2) + r;
          if (kabs >= SS || (qrow < NM1 && kabs >= NM1)) sv[jt][r] = -1e30f;
        }
    }

    // row max: 16 in-register + 2 cross-group shfl
    float mx = sv[0][0];
#pragma unroll
    for (int jt = 0; jt < 4; ++jt)
#pragma unroll
      for (int r = 0; r < 4; ++r) mx = fmaxf(mx, sv[jt][r]);
    mx = fmaxf(mx, __shfl_xor(mx, 16));
    mx = fmaxf(mx, __shfl_xor(mx, 32));

    const bool skip = __all(mx <= m_q);   // T13: no new max anywhere -> no rescale
    const float mn = skip ? m_q : fmaxf(m_q, mx);

    float pv[4][4];
    float ps = 0.f;
#pragma unroll
    for (int jt = 0; jt < 4; ++jt)
#pragma unroll
      for (int r = 0; r < 4; ++r) {
        float p = __expf(sv[jt][r] - mn);
        pv[jt][r] = p;
        ps += p;
      }
    ps += __shfl_xor(ps, 16);
    ps += __shfl_xor(ps, 32);

    if (!skip) {
      float alpha = __expf(m_q - mn);
      l_q = l_q * alpha + ps;
      m_q = mn;
      const int lg4 = lg * 4;
      float a0 = __shfl(alpha, lg4);
      float a1 = __shfl(alpha, lg4 + 1);
      float a2 = __shfl(alpha, lg4 + 2);
      float a3 = __shfl(alpha, lg4 + 3);
#pragma unroll
      for (int dt = 0; dt < 3; ++dt) {
        accO[dt][0] *= a0; accO[dt][1] *= a1;
        accO[dt][2] *= a2; accO[dt][3] *= a3;
      }
    } else {
      l_q += ps;
    }

    // pa[jc][i] = pv[jc*2 + (i>>2)][i&3] -- pure in-lane bf16 pack
    bf8 pa[2];
#pragma unroll
    for (int jc = 0; jc < 2; ++jc) {
      u32 w0 = (u32)f2bf(pv[jc * 2][0])     | ((u32)f2bf(pv[jc * 2][1]) << 16);
      u32 w1 = (u32)f2bf(pv[jc * 2][2])     | ((u32)f2bf(pv[jc * 2][3]) << 16);
      u32 w2 = (u32)f2bf(pv[jc * 2 + 1][0]) | ((u32)f2bf(pv[jc * 2 + 1][1]) << 16);
      u32 w3 = (u32)f2bf(pv[jc * 2 + 1][2]) | ((u32)f2bf(pv[jc * 2 + 1][3]) << 16);
      uint4 t = make_uint4(w0, w1, w2, w3);
      pa[jc] = *reinterpret_cast<bf8*>(&t);
    }

    // PV from LDS Vt tile (natural key order matches pi via construction)
#pragma unroll
    for (int dt = 0; dt < 3; ++dt) {
      int row = dt * 16 + l15;
#pragma unroll
      for (int jc = 0; jc < 2; ++jc) {
        int off = ((row << 7) + (jc << 6) + (lg << 4)) ^ ((row & 7) << 4);
        bf8 vb8 = *reinterpret_cast<const bf8*>(vb + off);
        accO[dt] = __builtin_amdgcn_mfma_f32_16x16x32_bf16(pa[jc], vb8, accO[dt], 0, 0, 0);
      }
    }
    __syncthreads();  // drains vmcnt (c+1 staged) + frees buf for c+2
    bsel ^= 1;
  }

  // epilogue: fetch 1/l for the 4 output rows (q = q0w + lg*4 + r)
  float linv = 1.0f / l_q;
  const int lg4 = lg * 4;
  float il[4];
#pragma unroll
  for (int r = 0; r < 4; ++r) il[r] = __shfl(linv, lg4 + r);
#pragma unroll
  for (int r = 0; r < 4; ++r) {
    int q = q0w + lg4 + r;
    if (q >= SS) continue;
#pragma unroll
    for (int dt = 0; dt < 3; ++dt) {
      int d = dt * 16 + l15;
      outb[((size_t)(b * SS + q)) * DD + h * DH + d] = f2bf(accO[dt][r] * il[r]);
    }
  }
}

// ---------------------------------------------------------------------------
// out = LayerNorm(a) * g + be, fp32 + bf16 mirror (residual pre-added in GEMM).
// ---------------------------------------------------------------------------
__global__ __launch_bounds__(128) void add_ln(const float* __restrict__ a,
                                              const float* __restrict__ g,
                                              const float* __restrict__ be,
                                              float* __restrict__ out,
                                              u16* __restrict__ outb) {
  __shared__ float p1[2], p2[2];
  const int row = blockIdx.x;
  const int t = threadIdx.x;
  const size_t base = (size_t)row * DD;
  float x0 = a[base + t];
  float x1 = a[base + t + 128];
  float x2 = a[base + t + 256];
  float s = x0 + x1 + x2;
#pragma unroll
  for (int off = 32; off; off >>= 1) s += __shfl_xor(s, off);
  if ((t & 63) == 0) p1[t >> 6] = s;
  __syncthreads();
  float mean = (p1[0] + p1[1]) * (1.0f / 384.0f);
  float d0 = x0 - mean, d1 = x1 - mean, d2 = x2 - mean;
  float vsum = d0 * d0 + d1 * d1 + d2 * d2;
#pragma unroll
  for (int off = 32; off; off >>= 1) vsum += __shfl_xor(vsum, off);
  if ((t & 63) == 0) p2[t >> 6] = vsum;
  __syncthreads();
  float var = (p2[0] + p2[1]) * (1.0f / 384.0f);
  float rs = rsqrtf(var + 1e-5f);
  float o0 = d0 * rs * g[t]       + be[t];
  float o1 = d1 * rs * g[t + 128] + be[t + 128];
  float o2 = d2 * rs * g[t + 256] + be[t + 256];
  out[base + t] = o0;        outb[base + t] = f2bf(o0);
  out[base + t + 128] = o1;  outb[base + t + 128] = f2bf(o1);
  out[base + t + 256] = o2;  outb[base + t + 256] = f2bf(o2);
}

__global__ void copy_out(const float* __restrict__ src, float* __restrict__ out) {
  int idx = blockIdx.x * 256 + threadIdx.x;
  if (idx >= BB * TT * DD) return;
  int d = idx % DD;
  int bt = idx / DD;
  int t = bt % TT;
  int b = bt / TT;
  out[idx] = src[((size_t)b * SS + (SS - TT) + t) * DD + d];
}

// ---------------------------------------------------------------------------
extern "C" void kernel_launch(void* const* d_in, const int* in_sizes, int n_in,
                              void* d_out, int out_size, void* d_ws, size_t ws_size,
                              hipStream_t stream) {
  const float* hand_t    = (const float*)d_in[0];
  const float* head_t    = (const float*)d_in[1];
  const float* hand_m1   = (const float*)d_in[2];
  const float* head_m1   = (const float*)d_in[3];
  const float* c_hand_t  = (const float*)d_in[4];
  const float* c_head_t  = (const float*)d_in[5];
  const float* c_hand_m1 = (const float*)d_in[6];
  const float* c_head_m1 = (const float*)d_in[7];
  const float* state_t   = (const float*)d_in[8];
  const float* state_m1  = (const float*)d_in[9];
  const float* tr_t      = (const float*)d_in[10];
  const float* tr_m1     = (const float*)d_in[11];
  const float* tok_m1    = (const float*)d_in[12];
  const float* tok_t     = (const float*)d_in[13];
  const float* Wq = (const float*)d_in[14];
  const float* bq = (const float*)d_in[15];
  const float* Wk = (const float*)d_in[16];
  const float* bk = (const float*)d_in[17];
  const float* Wv = (const float*)d_in[18];
  const float* bv = (const float*)d_in[19];
  const float* Wo = (const float*)d_in[20];
  const float* bo = (const float*)d_in[21];
  const float* W1 = (const float*)d_in[22];
  const float* b1 = (const float*)d_in[23];
  const float* W2 = (const float*)d_in[24];
  const float* b2 = (const float*)d_in[25];
  const float* g1 = (const float*)d_in[26];
  const float* be1 = (const float*)d_in[27];
  const float* g2 = (const float*)d_in[28];
  const float* be2 = (const float*)d_in[29];

  const size_t SRC_N = (size_t)BB * SS * DD;       // 3,176,448
  float* src    = (float*)d_ws;
  float* src2   = src + SRC_N;
  float* bufB   = src2 + SRC_N;
  float* coords = bufB + SRC_N;                    // 24,816
  float* bqkv   = coords + (size_t)BB * SS * 3;    // L*1152
  float2* trig  = (float2*)(bqkv + (size_t)LL * NQKV);   // B*S*24 float2
  u16* srcb  = (u16*)(trig + (size_t)BB * SS * 24);
  u16* src2b = srcb + SRC_N;
  u16* attnb = src2b + SRC_N;
  u16* qh  = attnb + SRC_N;
  const size_t QH_N = (size_t)BB * HH * SS * 64;   // 4,233,216
  u16* khb = qh + QH_N;
  u16* vtb = khb + QH_N;                           // 64*48*1088
  u16* hbf = vtb + (size_t)64 * DH * SSP;          // 12,705,792
  u16* wqkv_b = hbf + (size_t)MROWS * FFD;
  const size_t WD = (size_t)LL * DD * DD;
  const size_t WF = (size_t)LL * FFD * DD;
  u16* wo_bf = wqkv_b + (size_t)LL * NQKV * 384;
  u16* w1_bf = wo_bf + WD;
  u16* w2_bf = w1_bf + WF;

  const int M = MROWS;
  dim3 blk(256);

  build_src<<<(BB * SS * DD + 255) / 256, blk, 0, stream>>>(
      hand_t, head_t, hand_m1, head_m1, state_t, state_m1, tok_m1, tok_t, src, srcb);
  build_coords<<<(BB * SS * 3 + 255) / 256, blk, 0, stream>>>(
      c_hand_t, c_head_t, c_hand_m1, c_head_m1, tr_t, tr_m1, coords);
  build_trig<<<(BB * SS * 24 + 255) / 256, blk, 0, stream>>>(coords, trig);
  pack_qkv<<<(LL * NQKV * 96 + 255) / 256, blk, 0, stream>>>(Wq, Wk, Wv, wqkv_b);
  pack_bqkv<<<(LL * NQKV + 255) / 256, blk, 0, stream>>>(bq, bk, bv, bqkv);
  cvt_bf<<<(int)(WD / 4 + 255) / 256, blk, 0, stream>>>(Wo, wo_bf, (int)(WD / 4));
  cvt_bf<<<(int)(WF / 4 + 255) / 256, blk, 0, stream>>>(W1, w1_bf, (int)(WF / 4));
  cvt_bf<<<(int)(WF / 4 + 255) / 256, blk, 0, stream>>>(W2, w2_bf, (int)(WF / 4));
  pad_vt<<<(64 * DH * (SSP - SS) + 255) / 256, blk, 0, stream>>>(vtb);
  pad_qk<<<(64 * SS * 16 + 255) / 256, blk, 0, stream>>>(qh, khb);

  // XCD M-stripe grids: nxt * 72 (9 M-tiles per XCD, early-exit past 65)
  dim3 gqkv(18 * 72);   // N=1152, NT=2
  dim3 gwo(6 * 72);     // N=384,  NT=2
  dim3 gf1(12 * 72);    // N=1536, NT=4
  dim3 gf2(6 * 72);     // N=384,  NT=2
  dim3 gattn(17 * 8 * 8);

  for (int l = 0; l < LL; ++l) {
    const u16* Wqkv_l = wqkv_b + (size_t)l * NQKV * 384;
    const u16* Wo_l = wo_bf + (size_t)l * DD * DD;
    const u16* W1_l = w1_bf + (size_t)l * FFD * DD;
    const u16* W2_l = w2_bf + (size_t)l * DD * FFD;

    gemm_as<0, 2, 2><<<gqkv, blk, 0, stream>>>(srcb, Wqkv_l, bqkv + l * NQKV, trig,
                                               nullptr, nullptr, qh, khb, vtb, M, NQKV, DD);
    attn_mfma<<<gattn, blk, 0, stream>>>(qh, khb, vtb, attnb);
    gemm_as<0, 0, 2><<<gwo, blk, 0, stream>>>(attnb, Wo_l, bo + l * DD, nullptr,
                                              src, bufB, nullptr, nullptr, nullptr, M, DD, DD);
    add_ln<<<M, 128, 0, stream>>>(bufB, g1 + l * DD, be1 + l * DD, src2, src2b);
    gemm_as<1, 1, 4><<<gf1, blk, 0, stream>>>(src2b, W1_l, b1 + l * FFD, nullptr,
                                              nullptr, nullptr, hbf, nullptr, nullptr, M, FFD, DD);
    gemm_as<0, 0, 2><<<gf2, blk, 0, stream>>>(hbf, W2_l, b2 + l * DD, nullptr,
                                              src2, bufB, nullptr, nullptr, nullptr, M, DD, FFD);
    add_ln<<<M, 128, 0, stream>>>(bufB, g2 + l * DD, be2 + l * DD, src, srcb);
  }
  copy_out<<<(BB * TT * DD + 255) / 256, blk, 0, stream>>>(src, (float*)d_out);
}

// Round 9
// 1015.335 us; speedup vs baseline: 1.4870x; 1.0986x over previous
//
#include <hip/hip_runtime.h>
#include <hip/hip_bf16.h>
#include <math.h>

#define BB 8
#define NN 256
#define DD 384
#define LL 6
#define HH 8
#define FFD 1536
#define TT 4
#define DH 48
#define NM1 517      // T + 1 + 2N
#define SS 1034      // 2 * NM1
#define SSP 1088     // padded key stride for vt (17*64)
#define MROWS (BB*SS)
#define NQKV 1152
#define QSCALE 0.14433756729740643f

typedef unsigned short u16;
typedef unsigned int u32;
typedef short bf8 __attribute__((ext_vector_type(8)));
typedef float f32x4 __attribute__((ext_vector_type(4)));

__device__ __forceinline__ u16 f2bf(float f) {
  __hip_bfloat16 h = __float2bfloat16(f);
  return *reinterpret_cast<u16*>(&h);
}
__device__ __forceinline__ float bf2f(u16 u) {
  __hip_bfloat16 h;
  *reinterpret_cast<u16*>(&h) = u;
  return __bfloat162float(h);
}
// async global->LDS, 16B per lane; lds dest wave-uniform (HW adds lane*16)
__device__ __forceinline__ void async16(void* lds, const void* g) {
  __builtin_amdgcn_global_load_lds(
      (const __attribute__((address_space(1))) unsigned int*)g,
      (__attribute__((address_space(3))) unsigned int*)lds, 16, 0, 0);
}

// ---------------------------------------------------------------------------
// src assembly: fp32 residual + bf16 mirror.
// ---------------------------------------------------------------------------
__global__ void build_src(const float* __restrict__ hand_t, const float* __restrict__ head_t,
                          const float* __restrict__ hand_m1, const float* __restrict__ head_m1,
                          const float* __restrict__ state_t, const float* __restrict__ state_m1,
                          const float* __restrict__ tok_m1, const float* __restrict__ tok_t,
                          float* __restrict__ src, u16* __restrict__ srcb) {
  int idx = blockIdx.x * 256 + threadIdx.x;
  if (idx >= BB * SS * DD) return;
  int d = idx % DD;
  int bs = idx / DD;
  int s = bs % SS;
  int b = bs / SS;
  float val;
  if (s == 0)               val = state_m1[b * DD + d];
  else if (s <= NN)         val = hand_m1[((size_t)(b * NN + (s - 1))) * DD + d];
  else if (s <= 2 * NN)     val = head_m1[((size_t)(b * NN + (s - 1 - NN))) * DD + d];
  else if (s <= 2 * NN + TT) val = tok_m1[(s - (2 * NN + 1)) * DD + d];
  else if (s == NM1)        val = state_t[b * DD + d];
  else if (s <= NM1 + NN)   val = hand_t[((size_t)(b * NN + (s - NM1 - 1))) * DD + d];
  else if (s <= NM1 + 2 * NN) val = head_t[((size_t)(b * NN + (s - NM1 - 1 - NN))) * DD + d];
  else                      val = tok_t[(s - (NM1 + 2 * NN + 1)) * DD + d];
  src[idx] = val;
  srcb[idx] = f2bf(val);
}

__global__ void build_coords(const float* __restrict__ c_hand_t, const float* __restrict__ c_head_t,
                             const float* __restrict__ c_hand_m1, const float* __restrict__ c_head_m1,
                             const float* __restrict__ tr_t, const float* __restrict__ tr_m1,
                             float* __restrict__ coords) {
  int idx = blockIdx.x * 256 + threadIdx.x;
  if (idx >= BB * SS * 3) return;
  int a = idx % 3;
  int bs = idx / 3;
  int s = bs % SS;
  int b = bs / SS;
  float val;
  if (s == 0)               val = tr_m1[b * 3 + a];
  else if (s <= NN)         val = c_hand_m1[(b * NN + (s - 1)) * 3 + a];
  else if (s <= 2 * NN)     val = c_head_m1[(b * NN + (s - 1 - NN)) * 3 + a];
  else if (s <= 2 * NN + TT) val = tr_m1[b * 3 + a];
  else if (s == NM1)        val = tr_t[b * 3 + a];
  else if (s <= NM1 + NN)   val = c_hand_t[(b * NN + (s - NM1 - 1)) * 3 + a];
  else if (s <= NM1 + 2 * NN) val = c_head_t[(b * NN + (s - NM1 - 1 - NN)) * 3 + a];
  else                      val = tr_t[b * 3 + a];
  coords[idx] = val;
}

// cos/sin table: trig[(b*SS+s)*24 + axis*8 + i] = {cos, sin}(coords*inv_freq)
__global__ void build_trig(const float* __restrict__ coords, float2* __restrict__ trig) {
  int idx = blockIdx.x * 256 + threadIdx.x;
  if (idx >= BB * SS * 24) return;
  int i = idx & 7;
  int axis = (idx >> 3) % 3;
  int bs = idx / 24;
  float cv = coords[bs * 3 + axis];
  float inv = expf(-(float)i * 1.1512925464970229f);  // 10000^(-i/8)
  float ang = cv * inv;
  trig[idx] = make_float2(cosf(ang), sinf(ang));
}

// ---------------------------------------------------------------------------
// weight conversion / packing
// ---------------------------------------------------------------------------
__global__ void cvt_bf(const float* __restrict__ in, u16* __restrict__ out, int n4) {
  int idx = blockIdx.x * 256 + threadIdx.x;
  if (idx >= n4) return;
  float4 v = reinterpret_cast<const float4*>(in)[idx];
  short4 o;
  o.x = (short)f2bf(v.x); o.y = (short)f2bf(v.y);
  o.z = (short)f2bf(v.z); o.w = (short)f2bf(v.w);
  reinterpret_cast<short4*>(out)[idx] = o;
}

__global__ void pack_qkv(const float* __restrict__ Wq, const float* __restrict__ Wk,
                         const float* __restrict__ Wv, u16* __restrict__ wqkv) {
  int idx = blockIdx.x * 256 + threadIdx.x;
  const int TOTAL = LL * NQKV * 96;
  if (idx >= TOTAL) return;
  int k4 = idx % 96;
  int n = (idx / 96) % NQKV;
  int l = idx / (96 * NQKV);
  int sel = n / 384, nn = n - sel * 384;
  const float* W = (sel == 0) ? Wq : ((sel == 1) ? Wk : Wv);
  float4 v = *reinterpret_cast<const float4*>(W + ((size_t)l * 384 + nn) * 384 + k4 * 4);
  short4 o;
  o.x = (short)f2bf(v.x); o.y = (short)f2bf(v.y);
  o.z = (short)f2bf(v.z); o.w = (short)f2bf(v.w);
  *reinterpret_cast<short4*>(wqkv + ((size_t)(l * NQKV + n) * 384 + k4 * 4)) = o;
}

__global__ void pack_bqkv(const float* __restrict__ bq, const float* __restrict__ bk,
                          const float* __restrict__ bv, float* __restrict__ bqkv) {
  int idx = blockIdx.x * 256 + threadIdx.x;
  if (idx >= LL * NQKV) return;
  int n = idx % NQKV, l = idx / NQKV;
  int sel = n / 384, nn = n - sel * 384;
  const float* Bp = (sel == 0) ? bq : ((sel == 1) ? bk : bv);
  bqkv[idx] = Bp[l * 384 + nn];
}

// zero the padded key columns [SS, SSP) of vt
__global__ void pad_vt(u16* __restrict__ vt) {
  int idx = blockIdx.x * 256 + threadIdx.x;
  const int PADW = SSP - SS;
  if (idx >= 64 * DH * PADW) return;
  int c = idx % PADW;
  int rd = idx / PADW;
  vt[(size_t)rd * SSP + SS + c] = 0;
}

// zero the d=48..63 pad of qh/kh (GEMM epilogue writes only d<48)
__global__ void pad_qk(u16* __restrict__ qh, u16* __restrict__ kh) {
  int idx = blockIdx.x * 256 + threadIdx.x;
  if (idx >= 64 * SS * 16) return;
  int c = idx & 15;
  int row = idx >> 4;
  qh[(size_t)row * 64 + 48 + c] = 0;
  kh[(size_t)row * 64 + 48 + c] = 0;
}

// ---------------------------------------------------------------------------
// MFMA GEMM, bf16 in, async global->LDS staging, 2-phase double-buffered with
// COUNTED vmcnt. XCD M-STRIPE mapping (1-D grid of nxt*72 blocks; g%8 = XCD).
//   C[m,n] = sum_k A[m,k]*W[n,k] + bias[n]  (+ residual Rf for OUT==0)
//   EPI: 0 none, 1 exact GELU.
//   OUT: 0 fp32 row-major (+Rf), 1 bf16 row-major,
//        2 fused-QKV + RoPE via fp32 LDS-transpose epilogue (coalesced stores,
//          RoPE partner d^8 read from LDS — no shfl, bit-identical arithmetic).
//   NT:  n-fragments per wave (2 -> 128x64 tile, 4 -> 128x128 tile).
// ---------------------------------------------------------------------------
template <int EPI, int OUT, int NT>
__global__ __launch_bounds__(256) void gemm_as(
    const u16* __restrict__ Ab, const u16* __restrict__ Wb,
    const float* __restrict__ bias, const float2* __restrict__ trig,
    const float* __restrict__ Rf,
    float* __restrict__ Cf, u16* __restrict__ Cb,
    u16* __restrict__ Ck, u16* __restrict__ Cv,
    int M, int N, int K) {
  constexpr int BN = NT * 32;
  constexpr int BUFSZ = 16384 + NT * 4096;
  // OUT==2 epilogue reuses LDS as fp32 [128][65] tile (33280 B < 2*BUFSZ)
  __shared__ __align__(16) char sm[2 * BUFSZ];
  const int tid = threadIdx.x;

  // XCD M-stripe decomposition
  const int nxt = N / BN;
  const int Mt = (M + 127) >> 7;
  const int gL = blockIdx.x;
  const int x8 = gL & 7, jj = gL >> 3;
  const int mt_ = x8 * 9 + jj / nxt;
  if (mt_ >= Mt) return;
  const int bm = mt_ << 7, bn = (jj % nxt) * BN;

  const int lid = tid & 63, w = tid >> 6;
  const int wm = w >> 1, wn = w & 1;
  const int l15 = lid & 15, lg = lid >> 4;
  const int lr = lid >> 3, lu = lid & 7;
  const int swz = lu ^ lr;
  f32x4 acc[4][NT] = {};

  auto stage = [&](int bsel, int k0) {
    char* base = sm + bsel * BUFSZ;
#pragma unroll
    for (int q = 0; q < 4; ++q) {
      int row = w * 32 + q * 8 + lr;
      int grow = bm + row; if (grow >= M) grow = M - 1;
      async16(base + w * 4096 + q * 1024, Ab + (size_t)grow * K + k0 + (swz << 3));
    }
#pragma unroll
    for (int q = 0; q < NT; ++q) {
      int row = w * (NT * 8) + q * 8 + lr;
      async16(base + 16384 + w * (NT * 1024) + q * 1024,
              Wb + (size_t)(bn + row) * K + k0 + (swz << 3));
    }
  };

  stage(0, 0);   // 4+NT loads in flight per wave
  int bs = 0;

  for (int k0 = 0; k0 < K; k0 += 64) {
    if (k0 + 64 < K) {
      stage(bs ^ 1, k0 + 64);
      if constexpr (NT == 2)
        asm volatile("s_waitcnt vmcnt(6)" ::: "memory");   // tile t landed; t+1 in flight
      else
        asm volatile("s_waitcnt vmcnt(8)" ::: "memory");
    } else {
      asm volatile("s_waitcnt vmcnt(0)" ::: "memory");
    }
    __builtin_amdgcn_s_barrier();                       // all waves' tile t visible
    const char* base = sm + bs * BUFSZ;
    bf8 a[2][4], bfr[2][NT];
#pragma unroll
    for (int kf = 0; kf < 2; ++kf) {
#pragma unroll
      for (int mt = 0; mt < 4; ++mt) {
        int row = wm * 64 + mt * 16 + l15;
        int off = ((row << 7) + (kf << 6) + (lg << 4)) ^ ((row & 7) << 4);
        a[kf][mt] = *reinterpret_cast<const bf8*>(base + off);
      }
#pragma unroll
      for (int nt = 0; nt < NT; ++nt) {
        int row = wn * (NT * 16) + nt * 16 + l15;
        int off = 16384 + (((row << 7) + (kf << 6) + (lg << 4)) ^ ((row & 7) << 4));
        bfr[kf][nt] = *reinterpret_cast<const bf8*>(base + off);
      }
    }
#pragma unroll
    for (int kf = 0; kf < 2; ++kf)
#pragma unroll
      for (int mt = 0; mt < 4; ++mt)
#pragma unroll
        for (int nt = 0; nt < NT; ++nt)
          acc[mt][nt] = __builtin_amdgcn_mfma_f32_16x16x32_bf16(a[kf][mt], bfr[kf][nt], acc[mt][nt], 0, 0, 0);
    asm volatile("s_waitcnt lgkmcnt(0)" ::: "memory");  // all LDS reads of buf bs done
    __builtin_amdgcn_s_barrier();                       // WAR: buf bs free for next stage
    bs ^= 1;
  }

  if constexpr (OUT != 2) {
#pragma unroll
    for (int nt = 0; nt < NT; ++nt) {
      const int n = bn + wn * (NT * 16) + nt * 16 + l15;
      const float bsv = bias[n];
#pragma unroll
      for (int mt = 0; mt < 4; ++mt) {
        const int m0 = bm + wm * 64 + mt * 16 + lg * 4;
#pragma unroll
        for (int r = 0; r < 4; ++r) {
          int m = m0 + r;
          if (m >= M) continue;
          float v = acc[mt][nt][r] + bsv;
          if (EPI == 1) v = 0.5f * v * (1.0f + erff(v * 0.70710678118654752f));
          if (OUT == 0) Cf[(size_t)m * N + n] = v + Rf[(size_t)m * N + n];
          else          Cb[(size_t)m * N + n] = f2bf(v);
        }
      }
    }
  } else {
    // ---- fused-QKV epilogue: fp32 LDS transpose tile [128][65] ----
    float* tile = (float*)sm;
#pragma unroll
    for (int nt = 0; nt < NT; ++nt) {
      const int nl = wn * (NT * 16) + nt * 16 + l15;
      const float bsv = bias[bn + nl];
#pragma unroll
      for (int mt = 0; mt < 4; ++mt) {
#pragma unroll
        for (int r = 0; r < 4; ++r) {
          int ml = wm * 64 + mt * 16 + lg * 4 + r;
          tile[ml * 65 + nl] = acc[mt][nt][r] + bsv;
        }
      }
    }
    __syncthreads();
    const int bnm = bn % 384;
    const int sel = bn / 384;   // uniform per block (384 % BN == 0)
    if (sel < 2) {
      // lanes span d (coalesced qh/kh row stores); wave w owns rows w*32..+32
      u16* Cqk = (sel == 0) ? Cb : Ck;
      const int d = lid;
      const int nn_ = bnm + d;
      const int hdiv = nn_ / 48, hrem = nn_ - hdiv * 48;
      const int axis = hrem >> 4, ii = hrem & 7;
      const bool hi = (hrem & 8) != 0;
      for (int si = 0; si < 32; ++si) {
        int row = w * 32 + si;
        int m = bm + row;
        if (m >= M) break;
        int bI = m / SS, s = m - bI * SS;
        float v = tile[row * 65 + d];
        float p = tile[row * 65 + (d ^ 8)];
        float2 t = trig[(size_t)(bI * SS + s) * 24 + axis * 8 + ii];
        float outv = hi ? (p * t.y + v * t.x) : (v * t.x - p * t.y);
        if (sel == 0) outv *= QSCALE;
        Cqk[((size_t)(bI * HH + hdiv) * SS + s) * 64 + hrem] = f2bf(outv);
      }
    } else {
      // V: lanes span s (coalesced vt row stores)
      const int shalf = w >> 1, dpart = w & 1;
      const int srow = shalf * 64 + lid;
      const int m = bm + srow;
      if (m < M) {
        int bI = m / SS, s = m - bI * SS;
        for (int di = 0; di < 32; ++di) {
          int d = dpart * 32 + di;
          int nn_ = bnm + d;
          int hdiv = nn_ / 48, hrem = nn_ - hdiv * 48;
          Cv[((size_t)(bI * HH + hdiv) * DH + hrem) * SSP + s] = f2bf(tile[srow * 65 + d]);
        }
      }
    }
  }
}

// ---------------------------------------------------------------------------
// Flash attention v6: swapped QK^T + PERMUTED K staging so P needs NO
// cross-lane redistribution (see round 6).
// ---------------------------------------------------------------------------
__global__ __launch_bounds__(256) void attn_mfma(const u16* __restrict__ qh,
                                                 const u16* __restrict__ kh,
                                                 const u16* __restrict__ vt,
                                                 u16* __restrict__ outb) {
  // buf b: K 8KB @ b*14336, Vt 6KB @ b*14336+8192
  __shared__ __align__(16) char sm[28672];
  const int tid = threadIdx.x;
  const int lid = tid & 63, w = tid >> 6;
  const int l15 = lid & 15, lg = lid >> 4;
  const int lr = lid >> 3, lu = lid & 7;
  const int swz8 = (lu ^ lr) << 3;

  // XCD-grouped remap: f = low(3b: xcd) + 8*( gi*17 + qp17 )
  const int f = blockIdx.x;
  const int low = f & 7, j = f >> 3;
  const int gi = j / 17, qp17 = j - gi * 17;
  const int g = gi * 8 + low;          // (b,h) group
  const int h = g & 7, b = g >> 3;
  const int qblk = 16 - qp17;          // long (17-chunk) blocks first
  const int bh = b * HH + h;
  const int q0w = qblk * 64 + w * 16;
  const u16* kbase = kh + (size_t)bh * SS * 64;
  const u16* vbase = vt + (size_t)bh * DH * SSP;

  bf8 qf[2];
  {
    int row = q0w + l15; if (row >= SS) row = SS - 1;
    const u16* qp = qh + ((size_t)bh * SS + row) * 64;
    qf[0] = *reinterpret_cast<const bf8*>(qp + lg * 8);
    qf[1] = *reinterpret_cast<const bf8*>(qp + 32 + lg * 8);
  }
  const int qrow = q0w + l15;   // this lane's query (for mask + softmax state)

  float m_q = -1e30f, l_q = 0.f;
  f32x4 accO[3] = {};

  const int nch = (qblk < 8) ? 9 : 17;

  auto stage = [&](int bsel, int c) {
    const int j0 = c * 64;
    char* kb = sm + bsel * 14336;
    char* vb = kb + 8192;
#pragma unroll
    for (int qq = 0; qq < 2; ++qq) {
      int is = w * 2 + qq;
      int s = is * 8 + lr;                       // LDS row
      int jt_ = s >> 4, lgs = (s >> 2) & 3, rr = s & 3;
      int p = ((jt_ >> 1) << 5) + (lgs << 3) + ((jt_ & 1) << 2) + rr;  // pi(s)
      int jrow = j0 + p; if (jrow >= SS) jrow = SS - 1;
      async16(kb + is * 1024, kbase + (size_t)jrow * 64 + swz8);
    }
    async16(vb + w * 1024, vbase + (size_t)(w * 8 + lr) * SSP + j0 + swz8);
    if (w < 2)
      async16(vb + (4 + w) * 1024, vbase + (size_t)((4 + w) * 8 + lr) * SSP + j0 + swz8);
  };

  stage(0, 0);
  __syncthreads();
  int bsel = 0;

  for (int c = 0; c < nch; ++c) {
    if (c + 1 < nch) stage(bsel ^ 1, c + 1);
    const int j0 = c * 64;
    const char* kb = sm + bsel * 14336;
    const char* vb = kb + 8192;

    // QK^T swapped: sv[jt][r] = S[pi-slot = jt*16+lg*4+r][q = l15]
    f32x4 sv[4];
#pragma unroll
    for (int jt = 0; jt < 4; ++jt) {
      int row = jt * 16 + l15;
      int off0 = ((row << 7) + (lg << 4)) ^ ((row & 7) << 4);
      int off1 = ((row << 7) + 64 + (lg << 4)) ^ ((row & 7) << 4);
      bf8 kb0 = *reinterpret_cast<const bf8*>(kb + off0);
      bf8 kb1 = *reinterpret_cast<const bf8*>(kb + off1);
      f32x4 z = {};
      z = __builtin_amdgcn_mfma_f32_16x16x32_bf16(kb0, qf[0], z, 0, 0, 0);
      z = __builtin_amdgcn_mfma_f32_16x16x32_bf16(kb1, qf[1], z, 0, 0, 0);
      sv[jt] = z;
    }

    const bool domask = (c == 16) | ((q0w < NM1) & (c >= 8));
    if (domask) {
#pragma unroll
      for (int jt = 0; jt < 4; ++jt)
#pragma unroll
        for (int r = 0; r < 4; ++r) {
          // absolute key of slot (jt,lg,r) is j0 + pi(slot)
          int kabs = j0 + ((jt >> 1) << 5) + (lg << 3) + ((jt & 1) << 2) + r;
          if (kabs >= SS || (qrow < NM1 && kabs >= NM1)) sv[jt][r] = -1e30f;
        }
    }

    // row max: 16 in-register + 2 cross-group shfl
    float mx = sv[0][0];
#pragma unroll
    for (int jt = 0; jt < 4; ++jt)
#pragma unroll
      for (int r = 0; r < 4; ++r) mx = fmaxf(mx, sv[jt][r]);
    mx = fmaxf(mx, __shfl_xor(mx, 16));
    mx = fmaxf(mx, __shfl_xor(mx, 32));

    const bool skip = __all(mx <= m_q);   // T13: no new max anywhere -> no rescale
    const float mn = skip ? m_q : fmaxf(m_q, mx);

    float pv[4][4];
    float ps = 0.f;
#pragma unroll
    for (int jt = 0; jt < 4; ++jt)
#pragma unroll
      for (int r = 0; r < 4; ++r) {
        float p = __expf(sv[jt][r] - mn);
        pv[jt][r] = p;
        ps += p;
      }
    ps += __shfl_xor(ps, 16);
    ps += __shfl_xor(ps, 32);

    if (!skip) {
      float alpha = __expf(m_q - mn);
      l_q = l_q * alpha + ps;
      m_q = mn;
      const int lg4 = lg * 4;
      float a0 = __shfl(alpha, lg4);
      float a1 = __shfl(alpha, lg4 + 1);
      float a2 = __shfl(alpha, lg4 + 2);
      float a3 = __shfl(alpha, lg4 + 3);
#pragma unroll
      for (int dt = 0; dt < 3; ++dt) {
        accO[dt][0] *= a0; accO[dt][1] *= a1;
        accO[dt][2] *= a2; accO[dt][3] *= a3;
      }
    } else {
      l_q += ps;
    }

    // pa[jc][i] = pv[jc*2 + (i>>2)][i&3] -- pure in-lane bf16 pack
    bf8 pa[2];
#pragma unroll
    for (int jc = 0; jc < 2; ++jc) {
      u32 w0 = (u32)f2bf(pv[jc * 2][0])     | ((u32)f2bf(pv[jc * 2][1]) << 16);
      u32 w1 = (u32)f2bf(pv[jc * 2][2])     | ((u32)f2bf(pv[jc * 2][3]) << 16);
      u32 w2 = (u32)f2bf(pv[jc * 2 + 1][0]) | ((u32)f2bf(pv[jc * 2 + 1][1]) << 16);
      u32 w3 = (u32)f2bf(pv[jc * 2 + 1][2]) | ((u32)f2bf(pv[jc * 2 + 1][3]) << 16);
      uint4 t = make_uint4(w0, w1, w2, w3);
      pa[jc] = *reinterpret_cast<bf8*>(&t);
    }

    // PV from LDS Vt tile (natural key order matches pi via construction)
#pragma unroll
    for (int dt = 0; dt < 3; ++dt) {
      int row = dt * 16 + l15;
#pragma unroll
      for (int jc = 0; jc < 2; ++jc) {
        int off = ((row << 7) + (jc << 6) + (lg << 4)) ^ ((row & 7) << 4);
        bf8 vb8 = *reinterpret_cast<const bf8*>(vb + off);
        accO[dt] = __builtin_amdgcn_mfma_f32_16x16x32_bf16(pa[jc], vb8, accO[dt], 0, 0, 0);
      }
    }
    __syncthreads();  // drains vmcnt (c+1 staged) + frees buf for c+2
    bsel ^= 1;
  }

  // epilogue: fetch 1/l for the 4 output rows (q = q0w + lg*4 + r)
  float linv = 1.0f / l_q;
  const int lg4 = lg * 4;
  float il[4];
#pragma unroll
  for (int r = 0; r < 4; ++r) il[r] = __shfl(linv, lg4 + r);
#pragma unroll
  for (int r = 0; r < 4; ++r) {
    int q = q0w + lg4 + r;
    if (q >= SS) continue;
#pragma unroll
    for (int dt = 0; dt < 3; ++dt) {
      int d = dt * 16 + l15;
      outb[((size_t)(b * SS + q)) * DD + h * DH + d] = f2bf(accO[dt][r] * il[r]);
    }
  }
}

// ---------------------------------------------------------------------------
// out = LayerNorm(a) * g + be, fp32 + bf16 mirror (residual pre-added in GEMM).
// ---------------------------------------------------------------------------
__global__ __launch_bounds__(128) void add_ln(const float* __restrict__ a,
                                              const float* __restrict__ g,
                                              const float* __restrict__ be,
                                              float* __restrict__ out,
                                              u16* __restrict__ outb) {
  __shared__ float p1[2], p2[2];
  const int row = blockIdx.x;
  const int t = threadIdx.x;
  const size_t base = (size_t)row * DD;
  float x0 = a[base + t];
  float x1 = a[base + t + 128];
  float x2 = a[base + t + 256];
  float s = x0 + x1 + x2;
#pragma unroll
  for (int off = 32; off; off >>= 1) s += __shfl_xor(s, off);
  if ((t & 63) == 0) p1[t >> 6] = s;
  __syncthreads();
  float mean = (p1[0] + p1[1]) * (1.0f / 384.0f);
  float d0 = x0 - mean, d1 = x1 - mean, d2 = x2 - mean;
  float vsum = d0 * d0 + d1 * d1 + d2 * d2;
#pragma unroll
  for (int off = 32; off; off >>= 1) vsum += __shfl_xor(vsum, off);
  if ((t & 63) == 0) p2[t >> 6] = vsum;
  __syncthreads();
  float var = (p2[0] + p2[1]) * (1.0f / 384.0f);
  float rs = rsqrtf(var + 1e-5f);
  float o0 = d0 * rs * g[t]       + be[t];
  float o1 = d1 * rs * g[t + 128] + be[t + 128];
  float o2 = d2 * rs * g[t + 256] + be[t + 256];
  out[base + t] = o0;        outb[base + t] = f2bf(o0);
  out[base + t + 128] = o1;  outb[base + t + 128] = f2bf(o1);
  out[base + t + 256] = o2;  outb[base + t + 256] = f2bf(o2);
}

__global__ void copy_out(const float* __restrict__ src, float* __restrict__ out) {
  int idx = blockIdx.x * 256 + threadIdx.x;
  if (idx >= BB * TT * DD) return;
  int d = idx % DD;
  int bt = idx / DD;
  int t = bt % TT;
  int b = bt / TT;
  out[idx] = src[((size_t)b * SS + (SS - TT) + t) * DD + d];
}

// ---------------------------------------------------------------------------
extern "C" void kernel_launch(void* const* d_in, const int* in_sizes, int n_in,
                              void* d_out, int out_size, void* d_ws, size_t ws_size,
                              hipStream_t stream) {
  const float* hand_t    = (const float*)d_in[0];
  const float* head_t    = (const float*)d_in[1];
  const float* hand_m1   = (const float*)d_in[2];
  const float* head_m1   = (const float*)d_in[3];
  const float* c_hand_t  = (const float*)d_in[4];
  const float* c_head_t  = (const float*)d_in[5];
  const float* c_hand_m1 = (const float*)d_in[6];
  const float* c_head_m1 = (const float*)d_in[7];
  const float* state_t   = (const float*)d_in[8];
  const float* state_m1  = (const float*)d_in[9];
  const float* tr_t      = (const float*)d_in[10];
  const float* tr_m1     = (const float*)d_in[11];
  const float* tok_m1    = (const float*)d_in[12];
  const float* tok_t     = (const float*)d_in[13];
  const float* Wq = (const float*)d_in[14];
  const float* bq = (const float*)d_in[15];
  const float* Wk = (const float*)d_in[16];
  const float* bk = (const float*)d_in[17];
  const float* Wv = (const float*)d_in[18];
  const float* bv = (const float*)d_in[19];
  const float* Wo = (const float*)d_in[20];
  const float* bo = (const float*)d_in[21];
  const float* W1 = (const float*)d_in[22];
  const float* b1 = (const float*)d_in[23];
  const float* W2 = (const float*)d_in[24];
  const float* b2 = (const float*)d_in[25];
  const float* g1 = (const float*)d_in[26];
  const float* be1 = (const float*)d_in[27];
  const float* g2 = (const float*)d_in[28];
  const float* be2 = (const float*)d_in[29];

  const size_t SRC_N = (size_t)BB * SS * DD;       // 3,176,448
  float* src    = (float*)d_ws;
  float* src2   = src + SRC_N;
  float* bufB   = src2 + SRC_N;
  float* coords = bufB + SRC_N;                    // 24,816
  float* bqkv   = coords + (size_t)BB * SS * 3;    // L*1152
  float2* trig  = (float2*)(bqkv + (size_t)LL * NQKV);   // B*S*24 float2
  u16* srcb  = (u16*)(trig + (size_t)BB * SS * 24);
  u16* src2b = srcb + SRC_N;
  u16* attnb = src2b + SRC_N;
  u16* qh  = attnb + SRC_N;
  const size_t QH_N = (size_t)BB * HH * SS * 64;   // 4,233,216
  u16* khb = qh + QH_N;
  u16* vtb = khb + QH_N;                           // 64*48*1088
  u16* hbf = vtb + (size_t)64 * DH * SSP;          // 12,705,792
  u16* wqkv_b = hbf + (size_t)MROWS * FFD;
  const size_t WD = (size_t)LL * DD * DD;
  const size_t WF = (size_t)LL * FFD * DD;
  u16* wo_bf = wqkv_b + (size_t)LL * NQKV * 384;
  u16* w1_bf = wo_bf + WD;
  u16* w2_bf = w1_bf + WF;

  const int M = MROWS;
  dim3 blk(256);

  build_src<<<(BB * SS * DD + 255) / 256, blk, 0, stream>>>(
      hand_t, head_t, hand_m1, head_m1, state_t, state_m1, tok_m1, tok_t, src, srcb);
  build_coords<<<(BB * SS * 3 + 255) / 256, blk, 0, stream>>>(
      c_hand_t, c_head_t, c_hand_m1, c_head_m1, tr_t, tr_m1, coords);
  build_trig<<<(BB * SS * 24 + 255) / 256, blk, 0, stream>>>(coords, trig);
  pack_qkv<<<(LL * NQKV * 96 + 255) / 256, blk, 0, stream>>>(Wq, Wk, Wv, wqkv_b);
  pack_bqkv<<<(LL * NQKV + 255) / 256, blk, 0, stream>>>(bq, bk, bv, bqkv);
  cvt_bf<<<(int)(WD / 4 + 255) / 256, blk, 0, stream>>>(Wo, wo_bf, (int)(WD / 4));
  cvt_bf<<<(int)(WF / 4 + 255) / 256, blk, 0, stream>>>(W1, w1_bf, (int)(WF / 4));
  cvt_bf<<<(int)(WF / 4 + 255) / 256, blk, 0, stream>>>(W2, w2_bf, (int)(WF / 4));
  pad_vt<<<(64 * DH * (SSP - SS) + 255) / 256, blk, 0, stream>>>(vtb);
  pad_qk<<<(64 * SS * 16 + 255) / 256, blk, 0, stream>>>(qh, khb);

  // XCD M-stripe grids: nxt * 72 (9 M-tiles per XCD, early-exit past 65)
  dim3 gqkv(18 * 72);   // N=1152, NT=2
  dim3 gwo(6 * 72);     // N=384,  NT=2
  dim3 gf1(24 * 72);    // N=1536, NT=2
  dim3 gf2(6 * 72);     // N=384,  NT=2
  dim3 gattn(17 * 8 * 8);

  for (int l = 0; l < LL; ++l) {
    const u16* Wqkv_l = wqkv_b + (size_t)l * NQKV * 384;
    const u16* Wo_l = wo_bf + (size_t)l * DD * DD;
    const u16* W1_l = w1_bf + (size_t)l * FFD * DD;
    const u16* W2_l = w2_bf + (size_t)l * DD * FFD;

    gemm_as<0, 2, 2><<<gqkv, blk, 0, stream>>>(srcb, Wqkv_l, bqkv + l * NQKV, trig,
                                               nullptr, nullptr, qh, khb, vtb, M, NQKV, DD);
    attn_mfma<<<gattn, blk, 0, stream>>>(qh, khb, vtb, attnb);
    gemm_as<0, 0, 2><<<gwo, blk, 0, stream>>>(attnb, Wo_l, bo + l * DD, nullptr,
                                              src, bufB, nullptr, nullptr, nullptr, M, DD, DD);
    add_ln<<<M, 128, 0, stream>>>(bufB, g1 + l * DD, be1 + l * DD, src2, src2b);
    gemm_as<1, 1, 2><<<gf1, blk, 0, stream>>>(src2b, W1_l, b1 + l * FFD, nullptr,
                                              nullptr, nullptr, hbf, nullptr, nullptr, M, FFD, DD);
    gemm_as<0, 0, 2><<<gf2, blk, 0, stream>>>(hbf, W2_l, b2 + l * DD, nullptr,
                                              src2, bufB, nullptr, nullptr, nullptr, M, DD, FFD);
    add_ln<<<M, 128, 0, stream>>>(bufB, g2 + l * DD, be2 + l * DD, src, srcb);
  }
  copy_out<<<(BB * TT * DD + 255) / 256, blk, 0, stream>>>(src, (float*)d_out);
}

// Round 10
// 903.616 us; speedup vs baseline: 1.6709x; 1.1236x over previous
//
#include <hip/hip_runtime.h>
#include <hip/hip_bf16.h>
#include <math.h>

#define BB 8
#define NN 256
#define DD 384
#define LL 6
#define HH 8
#define FFD 1536
#define TT 4
#define DH 48
#define NM1 517      // T + 1 + 2N
#define SS 1034      // 2 * NM1
#define SSP 1088     // padded key stride for vt (17*64)
#define MROWS (BB*SS)
#define NQKV 1152
#define QSCALE 0.14433756729740643f

typedef unsigned short u16;
typedef unsigned int u32;
typedef short bf8 __attribute__((ext_vector_type(8)));
typedef float f32x4 __attribute__((ext_vector_type(4)));

__device__ __forceinline__ u16 f2bf(float f) {
  __hip_bfloat16 h = __float2bfloat16(f);
  return *reinterpret_cast<u16*>(&h);
}
__device__ __forceinline__ float bf2f(u16 u) {
  __hip_bfloat16 h;
  *reinterpret_cast<u16*>(&h) = u;
  return __bfloat162float(h);
}
// async global->LDS, 16B per lane; lds dest wave-uniform (HW adds lane*16)
__device__ __forceinline__ void async16(void* lds, const void* g) {
  __builtin_amdgcn_global_load_lds(
      (const __attribute__((address_space(1))) unsigned int*)g,
      (__attribute__((address_space(3))) unsigned int*)lds, 16, 0, 0);
}

// ---------------------------------------------------------------------------
// src assembly: fp32 residual + bf16 mirror.
// ---------------------------------------------------------------------------
__global__ void build_src(const float* __restrict__ hand_t, const float* __restrict__ head_t,
                          const float* __restrict__ hand_m1, const float* __restrict__ head_m1,
                          const float* __restrict__ state_t, const float* __restrict__ state_m1,
                          const float* __restrict__ tok_m1, const float* __restrict__ tok_t,
                          float* __restrict__ src, u16* __restrict__ srcb) {
  int idx = blockIdx.x * 256 + threadIdx.x;
  if (idx >= BB * SS * DD) return;
  int d = idx % DD;
  int bs = idx / DD;
  int s = bs % SS;
  int b = bs / SS;
  float val;
  if (s == 0)               val = state_m1[b * DD + d];
  else if (s <= NN)         val = hand_m1[((size_t)(b * NN + (s - 1))) * DD + d];
  else if (s <= 2 * NN)     val = head_m1[((size_t)(b * NN + (s - 1 - NN))) * DD + d];
  else if (s <= 2 * NN + TT) val = tok_m1[(s - (2 * NN + 1)) * DD + d];
  else if (s == NM1)        val = state_t[b * DD + d];
  else if (s <= NM1 + NN)   val = hand_t[((size_t)(b * NN + (s - NM1 - 1))) * DD + d];
  else if (s <= NM1 + 2 * NN) val = head_t[((size_t)(b * NN + (s - NM1 - 1 - NN))) * DD + d];
  else                      val = tok_t[(s - (NM1 + 2 * NN + 1)) * DD + d];
  src[idx] = val;
  srcb[idx] = f2bf(val);
}

__global__ void build_coords(const float* __restrict__ c_hand_t, const float* __restrict__ c_head_t,
                             const float* __restrict__ c_hand_m1, const float* __restrict__ c_head_m1,
                             const float* __restrict__ tr_t, const float* __restrict__ tr_m1,
                             float* __restrict__ coords) {
  int idx = blockIdx.x * 256 + threadIdx.x;
  if (idx >= BB * SS * 3) return;
  int a = idx % 3;
  int bs = idx / 3;
  int s = bs % SS;
  int b = bs / SS;
  float val;
  if (s == 0)               val = tr_m1[b * 3 + a];
  else if (s <= NN)         val = c_hand_m1[(b * NN + (s - 1)) * 3 + a];
  else if (s <= 2 * NN)     val = c_head_m1[(b * NN + (s - 1 - NN)) * 3 + a];
  else if (s <= 2 * NN + TT) val = tr_m1[b * 3 + a];
  else if (s == NM1)        val = tr_t[b * 3 + a];
  else if (s <= NM1 + NN)   val = c_hand_t[(b * NN + (s - NM1 - 1)) * 3 + a];
  else if (s <= NM1 + 2 * NN) val = c_head_t[(b * NN + (s - NM1 - 1 - NN)) * 3 + a];
  else                      val = tr_t[b * 3 + a];
  coords[idx] = val;
}

// cos/sin table: trig[(b*SS+s)*24 + axis*8 + i] = {cos, sin}(coords*inv_freq)
__global__ void build_trig(const float* __restrict__ coords, float2* __restrict__ trig) {
  int idx = blockIdx.x * 256 + threadIdx.x;
  if (idx >= BB * SS * 24) return;
  int i = idx & 7;
  int axis = (idx >> 3) % 3;
  int bs = idx / 24;
  float cv = coords[bs * 3 + axis];
  float inv = expf(-(float)i * 1.1512925464970229f);  // 10000^(-i/8)
  float ang = cv * inv;
  trig[idx] = make_float2(cosf(ang), sinf(ang));
}

// ---------------------------------------------------------------------------
// weight conversion / packing
// ---------------------------------------------------------------------------
__global__ void cvt_bf(const float* __restrict__ in, u16* __restrict__ out, int n4) {
  int idx = blockIdx.x * 256 + threadIdx.x;
  if (idx >= n4) return;
  float4 v = reinterpret_cast<const float4*>(in)[idx];
  short4 o;
  o.x = (short)f2bf(v.x); o.y = (short)f2bf(v.y);
  o.z = (short)f2bf(v.z); o.w = (short)f2bf(v.w);
  reinterpret_cast<short4*>(out)[idx] = o;
}

__global__ void pack_qkv(const float* __restrict__ Wq, const float* __restrict__ Wk,
                         const float* __restrict__ Wv, u16* __restrict__ wqkv) {
  int idx = blockIdx.x * 256 + threadIdx.x;
  const int TOTAL = LL * NQKV * 96;
  if (idx >= TOTAL) return;
  int k4 = idx % 96;
  int n = (idx / 96) % NQKV;
  int l = idx / (96 * NQKV);
  int sel = n / 384, nn = n - sel * 384;
  const float* W = (sel == 0) ? Wq : ((sel == 1) ? Wk : Wv);
  float4 v = *reinterpret_cast<const float4*>(W + ((size_t)l * 384 + nn) * 384 + k4 * 4);
  short4 o;
  o.x = (short)f2bf(v.x); o.y = (short)f2bf(v.y);
  o.z = (short)f2bf(v.z); o.w = (short)f2bf(v.w);
  *reinterpret_cast<short4*>(wqkv + ((size_t)(l * NQKV + n) * 384 + k4 * 4)) = o;
}

__global__ void pack_bqkv(const float* __restrict__ bq, const float* __restrict__ bk,
                          const float* __restrict__ bv, float* __restrict__ bqkv) {
  int idx = blockIdx.x * 256 + threadIdx.x;
  if (idx >= LL * NQKV) return;
  int n = idx % NQKV, l = idx / NQKV;
  int sel = n / 384, nn = n - sel * 384;
  const float* Bp = (sel == 0) ? bq : ((sel == 1) ? bk : bv);
  bqkv[idx] = Bp[l * 384 + nn];
}

// zero the padded key columns [SS, SSP) of vt
__global__ void pad_vt(u16* __restrict__ vt) {
  int idx = blockIdx.x * 256 + threadIdx.x;
  const int PADW = SSP - SS;
  if (idx >= 64 * DH * PADW) return;
  int c = idx % PADW;
  int rd = idx / PADW;
  vt[(size_t)rd * SSP + SS + c] = 0;
}

// zero the d=48..63 pad of qh/kh (GEMM epilogue writes only d<48)
__global__ void pad_qk(u16* __restrict__ qh, u16* __restrict__ kh) {
  int idx = blockIdx.x * 256 + threadIdx.x;
  if (idx >= 64 * SS * 16) return;
  int c = idx & 15;
  int row = idx >> 4;
  qh[(size_t)row * 64 + 48 + c] = 0;
  kh[(size_t)row * 64 + 48 + c] = 0;
}

// ---------------------------------------------------------------------------
// MFMA GEMM, bf16 in, async global->LDS staging, 2-phase double-buffered with
// COUNTED vmcnt. 512 threads = 8 waves on a 128x64 tile (wave owns 32x32):
// 2x TLP vs 4-wave version at the same 48KB LDS -> 24 waves/CU resident.
// XCD M-STRIPE mapping (1-D grid of nxt*72 blocks; g%8 = XCD).
//   C[m,n] = sum_k A[m,k]*W[n,k] + bias[n]  (+ residual Rf for OUT==0)
//   EPI: 0 none, 1 exact GELU.
//   OUT: 0 fp32 row-major (+Rf), 1 bf16 row-major,
//        2 fused-QKV + RoPE via fp32 LDS-transpose epilogue.
// ---------------------------------------------------------------------------
template <int EPI, int OUT>
__global__ __launch_bounds__(512) void gemm_as(
    const u16* __restrict__ Ab, const u16* __restrict__ Wb,
    const float* __restrict__ bias, const float2* __restrict__ trig,
    const float* __restrict__ Rf,
    float* __restrict__ Cf, u16* __restrict__ Cb,
    u16* __restrict__ Ck, u16* __restrict__ Cv,
    int M, int N, int K) {
  constexpr int BUFSZ = 24576;  // A 16KB + B 8KB
  __shared__ __align__(16) char sm[2 * BUFSZ];   // 48KB; OUT==2 reuses as fp32 [128][65]
  const int tid = threadIdx.x;

  // XCD M-stripe decomposition
  const int nxt = N >> 6;
  const int Mt = (M + 127) >> 7;
  const int gL = blockIdx.x;
  const int x8 = gL & 7, jj = gL >> 3;
  const int mt_ = x8 * 9 + jj / nxt;
  if (mt_ >= Mt) return;
  const int bm = mt_ << 7, bn = (jj % nxt) << 6;

  const int lid = tid & 63, w = tid >> 6;        // w in 0..7
  const int wm = w >> 1, wn = w & 1;             // wave owns (wm*32, wn*32) 32x32
  const int l15 = lid & 15, lg = lid >> 4;
  const int lr = lid >> 3, lu = lid & 7;
  const int swz = lu ^ lr;
  f32x4 acc[2][2] = {};

  auto stage = [&](int bsel, int k0) {
    char* base = sm + bsel * BUFSZ;
    // A: 128 rows; wave w stages rows w*16 .. w*16+15 (2 issues)
#pragma unroll
    for (int q = 0; q < 2; ++q) {
      int row = w * 16 + q * 8 + lr;
      int grow = bm + row; if (grow >= M) grow = M - 1;
      async16(base + w * 2048 + q * 1024, Ab + (size_t)grow * K + k0 + (swz << 3));
    }
    // B: 64 rows; wave w stages rows w*8 .. w*8+7 (1 issue)
    async16(base + 16384 + w * 1024, Wb + (size_t)(bn + w * 8 + lr) * K + k0 + (swz << 3));
  };

  stage(0, 0);   // 3 loads in flight per wave
  int bs = 0;

  for (int k0 = 0; k0 < K; k0 += 64) {
    if (k0 + 64 < K) {
      stage(bs ^ 1, k0 + 64);                           // +3 loads for t+1
      asm volatile("s_waitcnt vmcnt(3)" ::: "memory");  // tile t landed; t+1 in flight
    } else {
      asm volatile("s_waitcnt vmcnt(0)" ::: "memory");
    }
    __builtin_amdgcn_s_barrier();                       // all waves' tile t visible
    const char* base = sm + bs * BUFSZ;
    bf8 a[2][2], bfr[2][2];
#pragma unroll
    for (int kf = 0; kf < 2; ++kf) {
#pragma unroll
      for (int mt = 0; mt < 2; ++mt) {
        int row = wm * 32 + mt * 16 + l15;
        int off = ((row << 7) + (kf << 6) + (lg << 4)) ^ ((row & 7) << 4);
        a[kf][mt] = *reinterpret_cast<const bf8*>(base + off);
      }
#pragma unroll
      for (int nt = 0; nt < 2; ++nt) {
        int row = wn * 32 + nt * 16 + l15;
        int off = 16384 + (((row << 7) + (kf << 6) + (lg << 4)) ^ ((row & 7) << 4));
        bfr[kf][nt] = *reinterpret_cast<const bf8*>(base + off);
      }
    }
#pragma unroll
    for (int kf = 0; kf < 2; ++kf)
#pragma unroll
      for (int mt = 0; mt < 2; ++mt)
#pragma unroll
        for (int nt = 0; nt < 2; ++nt)
          acc[mt][nt] = __builtin_amdgcn_mfma_f32_16x16x32_bf16(a[kf][mt], bfr[kf][nt], acc[mt][nt], 0, 0, 0);
    asm volatile("s_waitcnt lgkmcnt(0)" ::: "memory");  // all LDS reads of buf bs done
    __builtin_amdgcn_s_barrier();                       // WAR: buf bs free for next stage
    bs ^= 1;
  }

  if constexpr (OUT != 2) {
#pragma unroll
    for (int nt = 0; nt < 2; ++nt) {
      const int n = bn + wn * 32 + nt * 16 + l15;
      const float bsv = bias[n];
#pragma unroll
      for (int mt = 0; mt < 2; ++mt) {
        const int m0 = bm + wm * 32 + mt * 16 + lg * 4;
#pragma unroll
        for (int r = 0; r < 4; ++r) {
          int m = m0 + r;
          if (m >= M) continue;
          float v = acc[mt][nt][r] + bsv;
          if (EPI == 1) v = 0.5f * v * (1.0f + erff(v * 0.70710678118654752f));
          if (OUT == 0) Cf[(size_t)m * N + n] = v + Rf[(size_t)m * N + n];
          else          Cb[(size_t)m * N + n] = f2bf(v);
        }
      }
    }
  } else {
    // ---- fused-QKV epilogue: fp32 LDS transpose tile [128][65] ----
    float* tile = (float*)sm;
#pragma unroll
    for (int nt = 0; nt < 2; ++nt) {
      const int nl = wn * 32 + nt * 16 + l15;
      const float bsv = bias[bn + nl];
#pragma unroll
      for (int mt = 0; mt < 2; ++mt) {
#pragma unroll
        for (int r = 0; r < 4; ++r) {
          int ml = wm * 32 + mt * 16 + lg * 4 + r;
          tile[ml * 65 + nl] = acc[mt][nt][r] + bsv;
        }
      }
    }
    __syncthreads();
    const int bnm = bn % 384;
    const int sel = bn / 384;   // uniform per block (384 % 64 == 0)
    if (sel < 2) {
      // lanes span d (coalesced qh/kh row stores); wave w owns rows w*16..+16
      u16* Cqk = (sel == 0) ? Cb : Ck;
      const int d = lid;
      const int nn_ = bnm + d;
      const int hdiv = nn_ / 48, hrem = nn_ - hdiv * 48;
      const int axis = hrem >> 4, ii = hrem & 7;
      const bool hi = (hrem & 8) != 0;
      for (int si = 0; si < 16; ++si) {
        int row = w * 16 + si;
        int m = bm + row;
        if (m >= M) break;
        int bI = m / SS, s = m - bI * SS;
        float v = tile[row * 65 + d];
        float p = tile[row * 65 + (d ^ 8)];
        float2 t = trig[(size_t)(bI * SS + s) * 24 + axis * 8 + ii];
        float outv = hi ? (p * t.y + v * t.x) : (v * t.x - p * t.y);
        if (sel == 0) outv *= QSCALE;
        Cqk[((size_t)(bI * HH + hdiv) * SS + s) * 64 + hrem] = f2bf(outv);
      }
    } else {
      // V: lanes span s (coalesced vt row stores); 512 thr = 128 rows x 4 d-strips
      const int srow = tid & 127, dq = tid >> 7;
      const int m = bm + srow;
      if (m < M) {
        int bI = m / SS, s = m - bI * SS;
        for (int di = 0; di < 16; ++di) {
          int d = dq * 16 + di;
          int nn_ = bnm + d;
          int hdiv = nn_ / 48, hrem = nn_ - hdiv * 48;
          Cv[((size_t)(bI * HH + hdiv) * DH + hrem) * SSP + s] = f2bf(tile[srow * 65 + d]);
        }
      }
    }
  }
}

// ---------------------------------------------------------------------------
// Flash attention v6: swapped QK^T + PERMUTED K staging so P needs NO
// cross-lane redistribution (see round 6). Unchanged from round 9.
// ---------------------------------------------------------------------------
__global__ __launch_bounds__(256) void attn_mfma(const u16* __restrict__ qh,
                                                 const u16* __restrict__ kh,
                                                 const u16* __restrict__ vt,
                                                 u16* __restrict__ outb) {
  // buf b: K 8KB @ b*14336, Vt 6KB @ b*14336+8192
  __shared__ __align__(16) char sm[28672];
  const int tid = threadIdx.x;
  const int lid = tid & 63, w = tid >> 6;
  const int l15 = lid & 15, lg = lid >> 4;
  const int lr = lid >> 3, lu = lid & 7;
  const int swz8 = (lu ^ lr) << 3;

  // XCD-grouped remap: f = low(3b: xcd) + 8*( gi*17 + qp17 )
  const int f = blockIdx.x;
  const int low = f & 7, j = f >> 3;
  const int gi = j / 17, qp17 = j - gi * 17;
  const int g = gi * 8 + low;          // (b,h) group
  const int h = g & 7, b = g >> 3;
  const int qblk = 16 - qp17;          // long (17-chunk) blocks first
  const int bh = b * HH + h;
  const int q0w = qblk * 64 + w * 16;
  const u16* kbase = kh + (size_t)bh * SS * 64;
  const u16* vbase = vt + (size_t)bh * DH * SSP;

  bf8 qf[2];
  {
    int row = q0w + l15; if (row >= SS) row = SS - 1;
    const u16* qp = qh + ((size_t)bh * SS + row) * 64;
    qf[0] = *reinterpret_cast<const bf8*>(qp + lg * 8);
    qf[1] = *reinterpret_cast<const bf8*>(qp + 32 + lg * 8);
  }
  const int qrow = q0w + l15;   // this lane's query (for mask + softmax state)

  float m_q = -1e30f, l_q = 0.f;
  f32x4 accO[3] = {};

  const int nch = (qblk < 8) ? 9 : 17;

  auto stage = [&](int bsel, int c) {
    const int j0 = c * 64;
    char* kb = sm + bsel * 14336;
    char* vb = kb + 8192;
#pragma unroll
    for (int qq = 0; qq < 2; ++qq) {
      int is = w * 2 + qq;
      int s = is * 8 + lr;                       // LDS row
      int jt_ = s >> 4, lgs = (s >> 2) & 3, rr = s & 3;
      int p = ((jt_ >> 1) << 5) + (lgs << 3) + ((jt_ & 1) << 2) + rr;  // pi(s)
      int jrow = j0 + p; if (jrow >= SS) jrow = SS - 1;
      async16(kb + is * 1024, kbase + (size_t)jrow * 64 + swz8);
    }
    async16(vb + w * 1024, vbase + (size_t)(w * 8 + lr) * SSP + j0 + swz8);
    if (w < 2)
      async16(vb + (4 + w) * 1024, vbase + (size_t)((4 + w) * 8 + lr) * SSP + j0 + swz8);
  };

  stage(0, 0);
  __syncthreads();
  int bsel = 0;

  for (int c = 0; c < nch; ++c) {
    if (c + 1 < nch) stage(bsel ^ 1, c + 1);
    const int j0 = c * 64;
    const char* kb = sm + bsel * 14336;
    const char* vb = kb + 8192;

    // QK^T swapped: sv[jt][r] = S[pi-slot = jt*16+lg*4+r][q = l15]
    f32x4 sv[4];
#pragma unroll
    for (int jt = 0; jt < 4; ++jt) {
      int row = jt * 16 + l15;
      int off0 = ((row << 7) + (lg << 4)) ^ ((row & 7) << 4);
      int off1 = ((row << 7) + 64 + (lg << 4)) ^ ((row & 7) << 4);
      bf8 kb0 = *reinterpret_cast<const bf8*>(kb + off0);
      bf8 kb1 = *reinterpret_cast<const bf8*>(kb + off1);
      f32x4 z = {};
      z = __builtin_amdgcn_mfma_f32_16x16x32_bf16(kb0, qf[0], z, 0, 0, 0);
      z = __builtin_amdgcn_mfma_f32_16x16x32_bf16(kb1, qf[1], z, 0, 0, 0);
      sv[jt] = z;
    }

    const bool domask = (c == 16) | ((q0w < NM1) & (c >= 8));
    if (domask) {
#pragma unroll
      for (int jt = 0; jt < 4; ++jt)
#pragma unroll
        for (int r = 0; r < 4; ++r) {
          // absolute key of slot (jt,lg,r) is j0 + pi(slot)
          int kabs = j0 + ((jt >> 1) << 5) + (lg << 3) + ((jt & 1) << 2) + r;
          if (kabs >= SS || (qrow < NM1 && kabs >= NM1)) sv[jt][r] = -1e30f;
        }
    }

    // row max: 16 in-register + 2 cross-group shfl
    float mx = sv[0][0];
#pragma unroll
    for (int jt = 0; jt < 4; ++jt)
#pragma unroll
      for (int r = 0; r < 4; ++r) mx = fmaxf(mx, sv[jt][r]);
    mx = fmaxf(mx, __shfl_xor(mx, 16));
    mx = fmaxf(mx, __shfl_xor(mx, 32));

    const bool skip = __all(mx <= m_q);   // T13: no new max anywhere -> no rescale
    const float mn = skip ? m_q : fmaxf(m_q, mx);

    float pv[4][4];
    float ps = 0.f;
#pragma unroll
    for (int jt = 0; jt < 4; ++jt)
#pragma unroll
      for (int r = 0; r < 4; ++r) {
        float p = __expf(sv[jt][r] - mn);
        pv[jt][r] = p;
        ps += p;
      }
    ps += __shfl_xor(ps, 16);
    ps += __shfl_xor(ps, 32);

    if (!skip) {
      float alpha = __expf(m_q - mn);
      l_q = l_q * alpha + ps;
      m_q = mn;
      const int lg4 = lg * 4;
      float a0 = __shfl(alpha, lg4);
      float a1 = __shfl(alpha, lg4 + 1);
      float a2 = __shfl(alpha, lg4 + 2);
      float a3 = __shfl(alpha, lg4 + 3);
#pragma unroll
      for (int dt = 0; dt < 3; ++dt) {
        accO[dt][0] *= a0; accO[dt][1] *= a1;
        accO[dt][2] *= a2; accO[dt][3] *= a3;
      }
    } else {
      l_q += ps;
    }

    // pa[jc][i] = pv[jc*2 + (i>>2)][i&3] -- pure in-lane bf16 pack
    bf8 pa[2];
#pragma unroll
    for (int jc = 0; jc < 2; ++jc) {
      u32 w0 = (u32)f2bf(pv[jc * 2][0])     | ((u32)f2bf(pv[jc * 2][1]) << 16);
      u32 w1 = (u32)f2bf(pv[jc * 2][2])     | ((u32)f2bf(pv[jc * 2][3]) << 16);
      u32 w2 = (u32)f2bf(pv[jc * 2 + 1][0]) | ((u32)f2bf(pv[jc * 2 + 1][1]) << 16);
      u32 w3 = (u32)f2bf(pv[jc * 2 + 1][2]) | ((u32)f2bf(pv[jc * 2 + 1][3]) << 16);
      uint4 t = make_uint4(w0, w1, w2, w3);
      pa[jc] = *reinterpret_cast<bf8*>(&t);
    }

    // PV from LDS Vt tile (natural key order matches pi via construction)
#pragma unroll
    for (int dt = 0; dt < 3; ++dt) {
      int row = dt * 16 + l15;
#pragma unroll
      for (int jc = 0; jc < 2; ++jc) {
        int off = ((row << 7) + (jc << 6) + (lg << 4)) ^ ((row & 7) << 4);
        bf8 vb8 = *reinterpret_cast<const bf8*>(vb + off);
        accO[dt] = __builtin_amdgcn_mfma_f32_16x16x32_bf16(pa[jc], vb8, accO[dt], 0, 0, 0);
      }
    }
    __syncthreads();  // drains vmcnt (c+1 staged) + frees buf for c+2
    bsel ^= 1;
  }

  // epilogue: fetch 1/l for the 4 output rows (q = q0w + lg*4 + r)
  float linv = 1.0f / l_q;
  const int lg4 = lg * 4;
  float il[4];
#pragma unroll
  for (int r = 0; r < 4; ++r) il[r] = __shfl(linv, lg4 + r);
#pragma unroll
  for (int r = 0; r < 4; ++r) {
    int q = q0w + lg4 + r;
    if (q >= SS) continue;
#pragma unroll
    for (int dt = 0; dt < 3; ++dt) {
      int d = dt * 16 + l15;
      outb[((size_t)(b * SS + q)) * DD + h * DH + d] = f2bf(accO[dt][r] * il[r]);
    }
  }
}

// ---------------------------------------------------------------------------
// out = LayerNorm(a) * g + be, fp32 + bf16 mirror (residual pre-added in GEMM).
// ---------------------------------------------------------------------------
__global__ __launch_bounds__(128) void add_ln(const float* __restrict__ a,
                                              const float* __restrict__ g,
                                              const float* __restrict__ be,
                                              float* __restrict__ out,
                                              u16* __restrict__ outb) {
  __shared__ float p1[2], p2[2];
  const int row = blockIdx.x;
  const int t = threadIdx.x;
  const size_t base = (size_t)row * DD;
  float x0 = a[base + t];
  float x1 = a[base + t + 128];
  float x2 = a[base + t + 256];
  float s = x0 + x1 + x2;
#pragma unroll
  for (int off = 32; off; off >>= 1) s += __shfl_xor(s, off);
  if ((t & 63) == 0) p1[t >> 6] = s;
  __syncthreads();
  float mean = (p1[0] + p1[1]) * (1.0f / 384.0f);
  float d0 = x0 - mean, d1 = x1 - mean, d2 = x2 - mean;
  float vsum = d0 * d0 + d1 * d1 + d2 * d2;
#pragma unroll
  for (int off = 32; off; off >>= 1) vsum += __shfl_xor(vsum, off);
  if ((t & 63) == 0) p2[t >> 6] = vsum;
  __syncthreads();
  float var = (p2[0] + p2[1]) * (1.0f / 384.0f);
  float rs = rsqrtf(var + 1e-5f);
  float o0 = d0 * rs * g[t]       + be[t];
  float o1 = d1 * rs * g[t + 128] + be[t + 128];
  float o2 = d2 * rs * g[t + 256] + be[t + 256];
  out[base + t] = o0;        outb[base + t] = f2bf(o0);
  out[base + t + 128] = o1;  outb[base + t + 128] = f2bf(o1);
  out[base + t + 256] = o2;  outb[base + t + 256] = f2bf(o2);
}

__global__ void copy_out(const float* __restrict__ src, float* __restrict__ out) {
  int idx = blockIdx.x * 256 + threadIdx.x;
  if (idx >= BB * TT * DD) return;
  int d = idx % DD;
  int bt = idx / DD;
  int t = bt % TT;
  int b = bt / TT;
  out[idx] = src[((size_t)b * SS + (SS - TT) + t) * DD + d];
}

// ---------------------------------------------------------------------------
extern "C" void kernel_launch(void* const* d_in, const int* in_sizes, int n_in,
                              void* d_out, int out_size, void* d_ws, size_t ws_size,
                              hipStream_t stream) {
  const float* hand_t    = (const float*)d_in[0];
  const float* head_t    = (const float*)d_in[1];
  const float* hand_m1   = (const float*)d_in[2];
  const float* head_m1   = (const float*)d_in[3];
  const float* c_hand_t  = (const float*)d_in[4];
  const float* c_head_t  = (const float*)d_in[5];
  const float* c_hand_m1 = (const float*)d_in[6];
  const float* c_head_m1 = (const float*)d_in[7];
  const float* state_t   = (const float*)d_in[8];
  const float* state_m1  = (const float*)d_in[9];
  const float* tr_t      = (const float*)d_in[10];
  const float* tr_m1     = (const float*)d_in[11];
  const float* tok_m1    = (const float*)d_in[12];
  const float* tok_t     = (const float*)d_in[13];
  const float* Wq = (const float*)d_in[14];
  const float* bq = (const float*)d_in[15];
  const float* Wk = (const float*)d_in[16];
  const float* bk = (const float*)d_in[17];
  const float* Wv = (const float*)d_in[18];
  const float* bv = (const float*)d_in[19];
  const float* Wo = (const float*)d_in[20];
  const float* bo = (const float*)d_in[21];
  const float* W1 = (const float*)d_in[22];
  const float* b1 = (const float*)d_in[23];
  const float* W2 = (const float*)d_in[24];
  const float* b2 = (const float*)d_in[25];
  const float* g1 = (const float*)d_in[26];
  const float* be1 = (const float*)d_in[27];
  const float* g2 = (const float*)d_in[28];
  const float* be2 = (const float*)d_in[29];

  const size_t SRC_N = (size_t)BB * SS * DD;       // 3,176,448
  float* src    = (float*)d_ws;
  float* src2   = src + SRC_N;
  float* bufB   = src2 + SRC_N;
  float* coords = bufB + SRC_N;                    // 24,816
  float* bqkv   = coords + (size_t)BB * SS * 3;    // L*1152
  float2* trig  = (float2*)(bqkv + (size_t)LL * NQKV);   // B*S*24 float2
  u16* srcb  = (u16*)(trig + (size_t)BB * SS * 24);
  u16* src2b = srcb + SRC_N;
  u16* attnb = src2b + SRC_N;
  u16* qh  = attnb + SRC_N;
  const size_t QH_N = (size_t)BB * HH * SS * 64;   // 4,233,216
  u16* khb = qh + QH_N;
  u16* vtb = khb + QH_N;                           // 64*48*1088
  u16* hbf = vtb + (size_t)64 * DH * SSP;          // 12,705,792
  u16* wqkv_b = hbf + (size_t)MROWS * FFD;
  const size_t WD = (size_t)LL * DD * DD;
  const size_t WF = (size_t)LL * FFD * DD;
  u16* wo_bf = wqkv_b + (size_t)LL * NQKV * 384;
  u16* w1_bf = wo_bf + WD;
  u16* w2_bf = w1_bf + WF;

  const int M = MROWS;
  dim3 blk(256);
  dim3 blk512(512);

  build_src<<<(BB * SS * DD + 255) / 256, blk, 0, stream>>>(
      hand_t, head_t, hand_m1, head_m1, state_t, state_m1, tok_m1, tok_t, src, srcb);
  build_coords<<<(BB * SS * 3 + 255) / 256, blk, 0, stream>>>(
      c_hand_t, c_head_t, c_hand_m1, c_head_m1, tr_t, tr_m1, coords);
  build_trig<<<(BB * SS * 24 + 255) / 256, blk, 0, stream>>>(coords, trig);
  pack_qkv<<<(LL * NQKV * 96 + 255) / 256, blk, 0, stream>>>(Wq, Wk, Wv, wqkv_b);
  pack_bqkv<<<(LL * NQKV + 255) / 256, blk, 0, stream>>>(bq, bk, bv, bqkv);
  cvt_bf<<<(int)(WD / 4 + 255) / 256, blk, 0, stream>>>(Wo, wo_bf, (int)(WD / 4));
  cvt_bf<<<(int)(WF / 4 + 255) / 256, blk, 0, stream>>>(W1, w1_bf, (int)(WF / 4));
  cvt_bf<<<(int)(WF / 4 + 255) / 256, blk, 0, stream>>>(W2, w2_bf, (int)(WF / 4));
  pad_vt<<<(64 * DH * (SSP - SS) + 255) / 256, blk, 0, stream>>>(vtb);
  pad_qk<<<(64 * SS * 16 + 255) / 256, blk, 0, stream>>>(qh, khb);

  // XCD M-stripe grids: nxt * 72 (9 M-tiles per XCD, early-exit past 65)
  dim3 gqkv(18 * 72);   // N=1152
  dim3 gwo(6 * 72);     // N=384
  dim3 gf1(24 * 72);    // N=1536
  dim3 gf2(6 * 72);     // N=384
  dim3 gattn(17 * 8 * 8);

  for (int l = 0; l < LL; ++l) {
    const u16* Wqkv_l = wqkv_b + (size_t)l * NQKV * 384;
    const u16* Wo_l = wo_bf + (size_t)l * DD * DD;
    const u16* W1_l = w1_bf + (size_t)l * FFD * DD;
    const u16* W2_l = w2_bf + (size_t)l * DD * FFD;

    gemm_as<0, 2><<<gqkv, blk512, 0, stream>>>(srcb, Wqkv_l, bqkv + l * NQKV, trig,
                                               nullptr, nullptr, qh, khb, vtb, M, NQKV, DD);
    attn_mfma<<<gattn, blk, 0, stream>>>(qh, khb, vtb, attnb);
    gemm_as<0, 0><<<gwo, blk512, 0, stream>>>(attnb, Wo_l, bo + l * DD, nullptr,
                                              src, bufB, nullptr, nullptr, nullptr, M, DD, DD);
    add_ln<<<M, 128, 0, stream>>>(bufB, g1 + l * DD, be1 + l * DD, src2, src2b);
    gemm_as<1, 1><<<gf1, blk512, 0, stream>>>(src2b, W1_l, b1 + l * FFD, nullptr,
                                              nullptr, nullptr, hbf, nullptr, nullptr, M, FFD, DD);
    gemm_as<0, 0><<<gf2, blk512, 0, stream>>>(hbf, W2_l, b2 + l * DD, nullptr,
                                              src2, bufB, nullptr, nullptr, nullptr, M, DD, FFD);
    add_ln<<<M, 128, 0, stream>>>(bufB, g2 + l * DD, be2 + l * DD, src, srcb);
  }
  copy_out<<<(BB * TT * DD + 255) / 256, blk, 0, stream>>>(src, (float*)d_out);
}